// Round 9
// baseline (750.759 us; speedup 1.0000x reference)
//
#include <hip/hip_runtime.h>

// ---------------------------------------------------------------------------
// RGCN (basis decomposition, 2 layers) + mean-pool.  v9 structure:
//   xw[r] = x @ W_r for ALL nodes (dense MFMA)            [k_xw1/k_xw2]
//   edges bucketed by dst>>8 (391 buckets, LDS counting sort, no global
//   atomics)                                              [k_bhist/k_bscat]
//   aggregation: per-bucket block, f32 LDS accumulator, gather xw rows
//   + ds_add_f32; epilogue merges self-loop               [k_bagg1/k_bagg2]
//
// ws layout (bytes):
//   W1f     us[8*4096]   @ 0            B-frags of W1 (bf16)
//   W2f     us[8*1024]   @ 65536
//   xbf     us[N*64]     @ 81920        x in bf16
//   agg1    us[N*64]     @ 12881920     layer-1 agg (becomes h)
//   agg2    us[N*16]     @ 25681920     layer-2 agg
//   payload int[E]       @ 28881920     (src*8+et)<<8 | dst&255, bucket-sorted
//   bh      int[nBins*128] @ 32881920   per-(bin,block) counts
//   bhs     int[nBins*128] @ 33082112   scanned bases
//   btot    int[512]     @ 33282304
//   boff    int[512]     @ 33284352
//   start   int[65]      @ 33286400
//   xw1     us[N*8*64]   @ 33286912     (102.4 MB; xw2 aliases)
// NEED ~135.7 MB (ws proven >= 166 MB in rounds 5-8)
// ---------------------------------------------------------------------------

typedef __attribute__((ext_vector_type(8))) short bf16x8;
typedef __attribute__((ext_vector_type(4))) float f32x4;

#define NBLK1 128   // blocks for bucket counting sort

__device__ __forceinline__ unsigned short f2bf(float f) {
    unsigned u = __float_as_uint(f);
    unsigned r = u + 0x7FFFu + ((u >> 16) & 1u);   // RNE
    return (unsigned short)(r >> 16);
}

__device__ __forceinline__ float bf2f(unsigned short u) {
    return __uint_as_float(((unsigned)u) << 16);
}

__device__ __forceinline__ float bcast(float v, int l) {
    return __uint_as_float(__builtin_amdgcn_readlane(__float_as_uint(v), l));
}

// ---- weights in B-fragment order (16x16x32 bf16): lane l holds
// B[k = kt*32+(l>>4)*8+j][n = nt*16+(l&15)], j=0..7
__global__ __launch_bounds__(256) void k_weights(
    const float* __restrict__ bases1, const float* __restrict__ coeff1,
    const float* __restrict__ bases2, const float* __restrict__ coeff2,
    unsigned short* __restrict__ W1f, unsigned short* __restrict__ W2f) {
    int r = blockIdx.x;
    int tid = threadIdx.x;
    float c1[8], c2[8];
#pragma unroll
    for (int b = 0; b < 8; ++b) { c1[b] = coeff1[r * 8 + b]; c2[b] = coeff2[r * 8 + b]; }
    for (int idx = tid; idx < 4096; idx += 256) {
        int j = idx & 7, lane = (idx >> 3) & 63, nt = (idx >> 9) & 3, kt = idx >> 11;
        int i = kt * 32 + ((lane >> 4) << 3) + j;
        int jo = nt * 16 + (lane & 15);
        float s = 0.f;
#pragma unroll
        for (int b = 0; b < 8; ++b) s = fmaf(c1[b], bases1[b * 4096 + i * 64 + jo], s);
        W1f[r * 4096 + idx] = f2bf(s);
    }
    for (int idx = tid; idx < 1024; idx += 256) {
        int j = idx & 7, lane = (idx >> 3) & 63, kt = idx >> 9;
        int i = kt * 32 + ((lane >> 4) << 3) + j;
        int jo = lane & 15;
        float s = 0.f;
#pragma unroll
        for (int b = 0; b < 8; ++b) s = fmaf(c2[b], bases2[b * 1024 + i * 16 + jo], s);
        W2f[r * 1024 + idx] = f2bf(s);
    }
}

// ---- self-loop layer1 + x->bf16 cast fused
__global__ __launch_bounds__(256) void k_lin1x(
    const float* __restrict__ x, const float* __restrict__ wself,
    const float* __restrict__ bias, unsigned short* __restrict__ agg,
    unsigned short* __restrict__ xbf, int nNodes) {
    int lane = threadIdx.x & 63;
    int gw = (int)((blockIdx.x * blockDim.x + threadIdx.x) >> 6);
    int nW = (int)((gridDim.x * blockDim.x) >> 6);
    float w[64];
#pragma unroll
    for (int i = 0; i < 64; ++i) w[i] = wself[i * 64 + lane];
    float bj = bias[lane];
    for (int n = gw; n < nNodes; n += nW) {
        float xv = x[(size_t)n * 64 + lane];
        xbf[(size_t)n * 64 + lane] = f2bf(xv);
        float a0 = 0.f, a1 = 0.f, a2 = 0.f, a3 = 0.f;
#pragma unroll
        for (int i = 0; i < 64; i += 4) {
            a0 = fmaf(bcast(xv, i + 0), w[i + 0], a0);
            a1 = fmaf(bcast(xv, i + 1), w[i + 1], a1);
            a2 = fmaf(bcast(xv, i + 2), w[i + 2], a2);
            a3 = fmaf(bcast(xv, i + 3), w[i + 3], a3);
        }
        agg[(size_t)n * 64 + lane] = f2bf(bj + ((a0 + a1) + (a2 + a3)));
    }
}

// ---- bucket counting sort by dst>>8: per-block LDS hist
__global__ __launch_bounds__(256) void k_bhist(
    const int* __restrict__ dst, int* __restrict__ bh, int nE, int nBins) {
    __shared__ int h[512];
    for (int i = threadIdx.x; i < 512; i += 256) h[i] = 0;
    __syncthreads();
    int blk = blockIdx.x;
    int ech = (nE + NBLK1 - 1) / NBLK1;
    int e0 = blk * ech, e1 = min(e0 + ech, nE);
    for (int e = e0 + threadIdx.x; e < e1; e += 256)
        atomicAdd(&h[dst[e] >> 8], 1);
    __syncthreads();
    for (int t = threadIdx.x; t < nBins; t += 256) bh[t * NBLK1 + blk] = h[t];
}

// exclusive scan within 256-chunks (reused for bh array)
__global__ __launch_bounds__(256) void k_scanblk(
    const int* __restrict__ in, int* __restrict__ outx,
    int* __restrict__ btot, int n) {
    __shared__ int sm[256];
    int tid = threadIdx.x;
    int i = blockIdx.x * 256 + tid;
    int d = (i < n) ? in[i] : 0;
    sm[tid] = d;
    __syncthreads();
#pragma unroll
    for (int off = 1; off < 256; off <<= 1) {
        int v = (tid >= off) ? sm[tid - off] : 0;
        __syncthreads();
        sm[tid] += v;
        __syncthreads();
    }
    if (i < n) outx[i] = sm[tid] - d;
    if (tid == 255) btot[blockIdx.x] = sm[255];
}

__global__ void k_scantop(const int* __restrict__ btot, int* __restrict__ boff, int nB) {
    __shared__ int sm[512];
    int t = threadIdx.x;
    int d = (t < nB) ? btot[t] : 0;
    sm[t] = d;
    __syncthreads();
#pragma unroll
    for (int off = 1; off < 512; off <<= 1) {
        int v = (t >= off) ? sm[t - off] : 0;
        __syncthreads();
        sm[t] += v;
        __syncthreads();
    }
    if (t < nB) boff[t] = sm[t] - d;
}

__global__ __launch_bounds__(256) void k_scanadd2(
    int* __restrict__ bhs, const int* __restrict__ boff, int n) {
    int i = blockIdx.x * 256 + threadIdx.x;
    if (i < n) bhs[i] += boff[i >> 8];
}

// scatter payload into bucket-sorted order (LDS cursors, no global atomics)
__global__ __launch_bounds__(256) void k_bscat(
    const int* __restrict__ dst, const int* __restrict__ src,
    const int* __restrict__ et, const int* __restrict__ bhs,
    int* __restrict__ payload, int nE, int nBins) {
    __shared__ int cur[512];
    int blk = blockIdx.x;
    for (int t = threadIdx.x; t < nBins; t += 256) cur[t] = bhs[t * NBLK1 + blk];
    __syncthreads();
    int ech = (nE + NBLK1 - 1) / NBLK1;
    int e0 = blk * ech, e1 = min(e0 + ech, nE);
    for (int e = e0 + threadIdx.x; e < e1; e += 256) {
        int d = dst[e];
        int pos = atomicAdd(&cur[d >> 8], 1);
        payload[pos] = ((src[e] * 8 + et[e]) << 8) | (d & 255);
    }
}

// ---- xw1[(n*8+r)*64] = bf16( x[n] @ W_r )  (dense MFMA)
__global__ __launch_bounds__(256) void k_xw1(
    const unsigned short* __restrict__ xbf,
    const unsigned short* __restrict__ W1f,
    unsigned short* __restrict__ xw1, int nNodes) {
    __shared__ unsigned lds[4][16 * 36];
    int lane = threadIdx.x & 63;
    int wid = (int)(threadIdx.x >> 6);
    int tile = blockIdx.x * 4 + wid;
    int n0 = tile * 16;
    if (n0 >= nNodes) return;
    int sA = n0 + (lane & 15);
    if (sA >= nNodes) sA = nNodes - 1;
    const unsigned short* xrow = xbf + (size_t)sA * 64 + ((lane >> 4) << 3);
    bf16x8 a[2];
    a[0] = *(const bf16x8*)(xrow);
    a[1] = *(const bf16x8*)(xrow + 32);
    unsigned* L = lds[wid];
    const int even = !(lane & 1);
    const int cpair = (lane & 14) >> 1;
    int row2 = lane >> 2, ch = lane & 3;
    int nOut = n0 + row2;
    for (int r = 0; r < 8; ++r) {
        const unsigned short* Wf = W1f + r * 4096;
        f32x4 z = {0.f, 0.f, 0.f, 0.f};
        f32x4 acc[4] = {z, z, z, z};
#pragma unroll
        for (int kt = 0; kt < 2; ++kt)
#pragma unroll
            for (int nt = 0; nt < 4; ++nt) {
                bf16x8 b = *(const bf16x8*)(Wf + (kt * 4 + nt) * 512 + lane * 8);
                acc[nt] = __builtin_amdgcn_mfma_f32_16x16x32_bf16(a[kt], b, acc[nt], 0, 0, 0);
            }
#pragma unroll
        for (int reg = 0; reg < 4; ++reg) {
            int row = ((lane >> 4) << 2) + reg;
#pragma unroll
            for (int nt = 0; nt < 4; ++nt) {
                float mine = acc[nt][reg];
                float oth = __shfl_xor(mine, 1, 64);
                unsigned pk = even ? ((unsigned)f2bf(mine) | ((unsigned)f2bf(oth) << 16))
                                   : ((unsigned)f2bf(oth) | ((unsigned)f2bf(mine) << 16));
                if (even ? (nt < 2) : (nt >= 2)) L[row * 36 + cpair + nt * 8] = pk;
            }
        }
        if (nOut < nNodes) {
            uint4 v0 = *(uint4*)&L[row2 * 36 + ch * 4];
            uint4 v1 = *(uint4*)&L[row2 * 36 + 16 + ch * 4];
            uint4* mp = (uint4*)(xw1 + ((size_t)nOut * 8 + r) * 64);
            mp[ch] = v0;
            mp[4 + ch] = v1;
        }
    }
}

// ---- bucket aggregation layer1: f32 LDS acc, gather xw1 rows
__global__ __launch_bounds__(1024) void k_bagg1(
    const unsigned short* __restrict__ xw1, const int* __restrict__ payload,
    const int* __restrict__ bhs, unsigned short* __restrict__ agg1,
    int nBins, int nNodes, int nE) {
    __shared__ float acc[256 * 65];
    for (int i = threadIdx.x; i < 256 * 65; i += 1024) acc[i] = 0.f;
    __syncthreads();
    int b = blockIdx.x;
    int e0 = bhs[b * NBLK1];
    int e1 = (b == nBins - 1) ? nE : bhs[(b + 1) * NBLK1];
    int lane = threadIdx.x & 63;
    int wv = (int)(threadIdx.x >> 6);   // 0..15
    int sub = lane >> 4;                // edge slot 0..3
    int gl = lane & 15;                 // col group (4 cols)
    for (int base = e0 + wv * 32; base < e1; base += 16 * 32) {
        uint2 m[8]; int dl[8];
#pragma unroll
        for (int j = 0; j < 8; ++j) {
            int e = base + j * 4 + sub;
            bool ok = e < e1;
            int pay = ok ? payload[e] : 0;
            int key = pay >> 8;
            dl[j] = pay & 255;
            if (ok) {
                m[j] = *(const uint2*)(xw1 + (size_t)key * 64 + gl * 4);
            } else {
                m[j].x = 0; m[j].y = 0; dl[j] = 0;
            }
        }
#pragma unroll
        for (int j = 0; j < 8; ++j) {
            float* ap = &acc[dl[j] * 65 + gl * 4];
            atomicAdd(ap + 0, bf2f((unsigned short)(m[j].x)));
            atomicAdd(ap + 1, bf2f((unsigned short)(m[j].x >> 16)));
            atomicAdd(ap + 2, bf2f((unsigned short)(m[j].y)));
            atomicAdd(ap + 3, bf2f((unsigned short)(m[j].y >> 16)));
        }
    }
    __syncthreads();
    int nbase = b << 8;
    for (int i = threadIdx.x; i < 256 * 16; i += 1024) {
        int n = nbase + (i >> 4);
        if (n >= nNodes) continue;
        int cg = (i & 15) * 4;
        uint2 v = *(const uint2*)(agg1 + (size_t)n * 64 + cg);
        const float* ap = &acc[(i >> 4) * 65 + cg];
        float s0 = bf2f((unsigned short)(v.x)) + ap[0];
        float s1 = bf2f((unsigned short)(v.x >> 16)) + ap[1];
        float s2 = bf2f((unsigned short)(v.y)) + ap[2];
        float s3 = bf2f((unsigned short)(v.y >> 16)) + ap[3];
        uint2 p;
        p.x = (unsigned)f2bf(s0) | ((unsigned)f2bf(s1) << 16);
        p.y = (unsigned)f2bf(s2) | ((unsigned)f2bf(s3) << 16);
        *(uint2*)(agg1 + (size_t)n * 64 + cg) = p;
    }
}

// ---- relu (in-place) + self-loop layer2 -> agg2 init
__global__ __launch_bounds__(256) void k_lin2(
    unsigned short* __restrict__ agg1, const float* __restrict__ wself,
    const float* __restrict__ bias, unsigned short* __restrict__ agg2, int nNodes) {
    int lane = threadIdx.x & 63;
    int j = lane & 15;
    int gw = (int)((blockIdx.x * blockDim.x + threadIdx.x) >> 6);
    int nW = (int)((gridDim.x * blockDim.x) >> 6);
    float w[64];
#pragma unroll
    for (int i = 0; i < 64; ++i) w[i] = wself[i * 16 + j];
    float bj = bias[j];
    for (int n = gw; n < nNodes; n += nW) {
        unsigned short raw = agg1[(size_t)n * 64 + lane];
        unsigned short rbf = (raw & 0x8000u) ? (unsigned short)0 : raw;
        agg1[(size_t)n * 64 + lane] = rbf;          // h in place
        float hv = bf2f(rbf);
        float a0 = 0.f, a1 = 0.f, a2 = 0.f, a3 = 0.f;
#pragma unroll
        for (int i = 0; i < 64; i += 4) {
            a0 = fmaf(bcast(hv, i + 0), w[i + 0], a0);
            a1 = fmaf(bcast(hv, i + 1), w[i + 1], a1);
            a2 = fmaf(bcast(hv, i + 2), w[i + 2], a2);
            a3 = fmaf(bcast(hv, i + 3), w[i + 3], a3);
        }
        if (lane < 16) agg2[(size_t)n * 16 + lane] = f2bf(bj + ((a0 + a1) + (a2 + a3)));
    }
}

// ---- xw2[(n*8+r)*16] = bf16( h[n] @ W2_r )
__global__ __launch_bounds__(256) void k_xw2(
    const unsigned short* __restrict__ h,
    const unsigned short* __restrict__ W2f,
    unsigned short* __restrict__ xw2, int nNodes) {
    __shared__ unsigned lds[4][16 * 12];
    int lane = threadIdx.x & 63;
    int wid = (int)(threadIdx.x >> 6);
    int tile = blockIdx.x * 4 + wid;
    int n0 = tile * 16;
    if (n0 >= nNodes) return;
    int sA = n0 + (lane & 15);
    if (sA >= nNodes) sA = nNodes - 1;
    const unsigned short* hrow = h + (size_t)sA * 64 + ((lane >> 4) << 3);
    bf16x8 a[2];
    a[0] = *(const bf16x8*)(hrow);
    a[1] = *(const bf16x8*)(hrow + 32);
    unsigned* L = lds[wid];
    const int even = !(lane & 1);
    const int cpair = (lane & 14) >> 1;
    int row2 = lane >> 1, ch = lane & 1;
    int nOut = n0 + row2;
    for (int r = 0; r < 8; ++r) {
        const unsigned short* Wf = W2f + r * 1024;
        bf16x8 b0 = *(const bf16x8*)(Wf + lane * 8);
        bf16x8 b1 = *(const bf16x8*)(Wf + 512 + lane * 8);
        f32x4 acc = {0.f, 0.f, 0.f, 0.f};
        acc = __builtin_amdgcn_mfma_f32_16x16x32_bf16(a[0], b0, acc, 0, 0, 0);
        acc = __builtin_amdgcn_mfma_f32_16x16x32_bf16(a[1], b1, acc, 0, 0, 0);
#pragma unroll
        for (int reg = 0; reg < 4; ++reg) {
            int row = ((lane >> 4) << 2) + reg;
            float mine = acc[reg];
            float oth = __shfl_xor(mine, 1, 64);
            unsigned pk = even ? ((unsigned)f2bf(mine) | ((unsigned)f2bf(oth) << 16))
                               : ((unsigned)f2bf(oth) | ((unsigned)f2bf(mine) << 16));
            if (even ? (reg < 2) : (reg >= 2)) L[row * 12 + cpair] = pk;
        }
        if (lane < 32 && nOut < nNodes) {
            uint4 v = *(uint4*)&L[row2 * 12 + ch * 4];
            ((uint4*)(xw2 + ((size_t)nOut * 8 + r) * 16))[ch] = v;
        }
    }
}

// ---- bucket aggregation layer2
__global__ __launch_bounds__(1024) void k_bagg2(
    const unsigned short* __restrict__ xw2, const int* __restrict__ payload,
    const int* __restrict__ bhs, unsigned short* __restrict__ agg2,
    int nBins, int nNodes, int nE) {
    __shared__ float acc[256 * 17];
    for (int i = threadIdx.x; i < 256 * 17; i += 1024) acc[i] = 0.f;
    __syncthreads();
    int b = blockIdx.x;
    int e0 = bhs[b * NBLK1];
    int e1 = (b == nBins - 1) ? nE : bhs[(b + 1) * NBLK1];
    int lane = threadIdx.x & 63;
    int wv = (int)(threadIdx.x >> 6);
    int sub = lane >> 2;                // edge slot 0..15
    int gl = lane & 3;                  // col group (4 cols)
    for (int base = e0 + wv * 128; base < e1; base += 16 * 128) {
        uint2 m[8]; int dl[8];
#pragma unroll
        for (int j = 0; j < 8; ++j) {
            int e = base + j * 16 + sub;
            bool ok = e < e1;
            int pay = ok ? payload[e] : 0;
            int key = pay >> 8;
            dl[j] = pay & 255;
            if (ok) {
                m[j] = *(const uint2*)(xw2 + (size_t)key * 16 + gl * 4);
            } else {
                m[j].x = 0; m[j].y = 0; dl[j] = 0;
            }
        }
#pragma unroll
        for (int j = 0; j < 8; ++j) {
            float* ap = &acc[dl[j] * 17 + gl * 4];
            atomicAdd(ap + 0, bf2f((unsigned short)(m[j].x)));
            atomicAdd(ap + 1, bf2f((unsigned short)(m[j].x >> 16)));
            atomicAdd(ap + 2, bf2f((unsigned short)(m[j].y)));
            atomicAdd(ap + 3, bf2f((unsigned short)(m[j].y >> 16)));
        }
    }
    __syncthreads();
    int nbase = b << 8;
    for (int i = threadIdx.x; i < 256 * 4; i += 1024) {
        int n = nbase + (i >> 2);
        if (n >= nNodes) continue;
        int cg = (i & 3) * 4;
        uint2 v = *(const uint2*)(agg2 + (size_t)n * 16 + cg);
        const float* ap = &acc[(i >> 2) * 17 + cg];
        float s0 = bf2f((unsigned short)(v.x)) + ap[0];
        float s1 = bf2f((unsigned short)(v.x >> 16)) + ap[1];
        float s2 = bf2f((unsigned short)(v.y)) + ap[2];
        float s3 = bf2f((unsigned short)(v.y >> 16)) + ap[3];
        uint2 p;
        p.x = (unsigned)f2bf(s0) | ((unsigned)f2bf(s1) << 16);
        p.y = (unsigned)f2bf(s2) | ((unsigned)f2bf(s3) << 16);
        *(uint2*)(agg2 + (size_t)n * 16 + cg) = p;
    }
}

__global__ void k_bounds(const int* __restrict__ gid, int* __restrict__ start, int nNodes) {
    int t = blockIdx.x * blockDim.x + threadIdx.x;
    if (t > 64) return;
    int lo = 0, hi = nNodes;
    while (lo < hi) {
        int mid = (lo + hi) >> 1;
        if (gid[mid] < t) lo = mid + 1; else hi = mid;
    }
    start[t] = lo;
}

__global__ __launch_bounds__(256) void k_pool(
    const unsigned short* __restrict__ agg2, const int* __restrict__ start,
    float* __restrict__ out) {
    __shared__ float sm[256];
    int g = blockIdx.x;
    int t = threadIdx.x;
    int c = t & 15, idx = t >> 4;
    int s0 = start[g], s1 = start[g + 1];
    float acc = 0.f;
    for (int n = s0 + idx; n < s1; n += 16) acc += fmaxf(bf2f(agg2[(size_t)n * 16 + c]), 0.f);
    sm[t] = acc;
    __syncthreads();
#pragma unroll
    for (int off = 128; off >= 16; off >>= 1) {
        if (t < off) sm[t] += sm[t + off];
        __syncthreads();
    }
    if (t < 16) {
        float cnt = (float)(s1 - s0);
        out[g * 16 + t] = sm[t] / fmaxf(cnt, 1.f);
    }
}

extern "C" void kernel_launch(void* const* d_in, const int* in_sizes, int n_in,
                              void* d_out, int out_size, void* d_ws, size_t ws_size,
                              hipStream_t stream) {
    const float* x      = (const float*)d_in[0];
    const int*   src    = (const int*)d_in[1];
    const int*   dst    = (const int*)d_in[2];
    const int*   et     = (const int*)d_in[3];
    const int*   gid    = (const int*)d_in[4];
    const float* bases1 = (const float*)d_in[5];
    const float* coeff1 = (const float*)d_in[6];
    const float* wself1 = (const float*)d_in[7];
    const float* bias1  = (const float*)d_in[8];
    const float* bases2 = (const float*)d_in[9];
    const float* coeff2 = (const float*)d_in[10];
    const float* wself2 = (const float*)d_in[11];
    const float* bias2  = (const float*)d_in[12];
    float* out = (float*)d_out;

    int nNodes = in_sizes[0] / 64;
    int nE = in_sizes[1];
    int nBins = (nNodes + 255) >> 8;
    int nBh = nBins * NBLK1;

    char* ws = (char*)d_ws;
    unsigned short* W1f  = (unsigned short*)(ws);
    unsigned short* W2f  = (unsigned short*)(ws + 65536);
    unsigned short* xbf  = (unsigned short*)(ws + 81920);
    unsigned short* agg1 = (unsigned short*)(ws + 12881920);
    unsigned short* agg2 = (unsigned short*)(ws + 25681920);
    int*   payload = (int*)(ws + 28881920);
    int*   bh      = (int*)(ws + 32881920);
    int*   bhs     = (int*)(ws + 33082112);
    int*   btot    = (int*)(ws + 33282304);
    int*   boff    = (int*)(ws + 33284352);
    int*   start   = (int*)(ws + 33286400);
    unsigned short* xw1 = (unsigned short*)(ws + 33286912);
    unsigned short* xw2 = xw1;   // layer-2 reuses xw1 space

    int tiles = (nNodes + 15) / 16;
    int xwb = (tiles + 3) / 4;
    int scb = (nBh + 255) / 256;

    hipLaunchKernelGGL(k_weights, dim3(8), dim3(256), 0, stream,
                       bases1, coeff1, bases2, coeff2, W1f, W2f);
    hipLaunchKernelGGL(k_lin1x, dim3(512), dim3(256), 0, stream,
                       x, wself1, bias1, agg1, xbf, nNodes);
    hipLaunchKernelGGL(k_bhist, dim3(NBLK1), dim3(256), 0, stream,
                       dst, bh, nE, nBins);
    hipLaunchKernelGGL(k_scanblk, dim3(scb), dim3(256), 0, stream,
                       bh, bhs, btot, nBh);
    hipLaunchKernelGGL(k_scantop, dim3(1), dim3(512), 0, stream, btot, boff, scb);
    hipLaunchKernelGGL(k_scanadd2, dim3(scb), dim3(256), 0, stream,
                       bhs, boff, nBh);
    hipLaunchKernelGGL(k_bscat, dim3(NBLK1), dim3(256), 0, stream,
                       dst, src, et, bhs, payload, nE, nBins);
    hipLaunchKernelGGL(k_xw1, dim3(xwb), dim3(256), 0, stream,
                       xbf, W1f, xw1, nNodes);
    hipLaunchKernelGGL(k_bagg1, dim3(nBins), dim3(1024), 0, stream,
                       xw1, payload, bhs, agg1, nBins, nNodes, nE);
    hipLaunchKernelGGL(k_lin2, dim3(512), dim3(256), 0, stream,
                       agg1, wself2, bias2, agg2, nNodes);
    hipLaunchKernelGGL(k_xw2, dim3(xwb), dim3(256), 0, stream,
                       agg1, W2f, xw2, nNodes);
    hipLaunchKernelGGL(k_bagg2, dim3(nBins), dim3(1024), 0, stream,
                       xw2, payload, bhs, agg2, nBins, nNodes, nE);
    hipLaunchKernelGGL(k_bounds, dim3(1), dim3(128), 0, stream, gid, start, nNodes);
    hipLaunchKernelGGL(k_pool, dim3(64), dim3(256), 0, stream, agg2, start, out);
}

// Round 10
// 278.826 us; speedup vs baseline: 2.6926x; 2.6926x over previous
//
#include <hip/hip_runtime.h>

// ---------------------------------------------------------------------------
// RGCN (basis decomposition, 2 layers) + mean-pool.  v10 = v8 structure
// (dense xw MFMA + gather/segment-sum) with the CSR construction replaced:
//   v8: 1M global-atomic hist + 1M global-atomic rank (~110us, 70MB scatter)
//   v10: LDS int-atomic bucket sort by dst>>8 + per-bucket LDS refine
//        -> same skey/nodeoff CSR, sequential writes, no global atomics.
// (v9's f32-LDS-atomic aggregation reverted: float LDS atomics serialize
//  pathologically, 441us at 2% VALU.)
//
// ws layout (bytes):
//   W1f     us[8*4096]     @ 0           B-frags of W1 (bf16)
//   W2f     us[8*1024]     @ 65536
//   xbf     us[N*64]       @ 81920       x in bf16
//   agg1    us[N*64]       @ 12881920    layer-1 agg (becomes h)
//   agg2    us[N*16]       @ 25681920    layer-2 agg
//   payload int[E]         @ 28881920    (src*8+et)<<8 | dst&255, bucket-sorted
//   skey    int[E]         @ 32881920    src*8+et, dst-sorted (CSR payload)
//   nodeoff int[N+1]       @ 36881920
//   bh      int[nBins*128] @ 37282048    per-(bin,block) counts
//   bhs     int[nBins*128] @ 37482240
//   btot    int[512]       @ 37682432
//   boff    int[512]       @ 37684480
//   start   int[65]        @ 37686528
//   xw1     us[N*8*64]     @ 37687040    (102.4 MB; xw2 aliases)
// NEED ~140.1 MB (ws proven >= 166 MB in rounds 5-8)
// ---------------------------------------------------------------------------

typedef __attribute__((ext_vector_type(8))) short bf16x8;
typedef __attribute__((ext_vector_type(4))) float f32x4;

#define NBLK1 128   // blocks for bucket counting sort

__device__ __forceinline__ unsigned short f2bf(float f) {
    unsigned u = __float_as_uint(f);
    unsigned r = u + 0x7FFFu + ((u >> 16) & 1u);   // RNE
    return (unsigned short)(r >> 16);
}

__device__ __forceinline__ float bf2f(unsigned short u) {
    return __uint_as_float(((unsigned)u) << 16);
}

__device__ __forceinline__ float bcast(float v, int l) {
    return __uint_as_float(__builtin_amdgcn_readlane(__float_as_uint(v), l));
}

// ---- weights in B-fragment order (16x16x32 bf16): lane l holds
// B[k = kt*32+(l>>4)*8+j][n = nt*16+(l&15)], j=0..7
__global__ __launch_bounds__(256) void k_weights(
    const float* __restrict__ bases1, const float* __restrict__ coeff1,
    const float* __restrict__ bases2, const float* __restrict__ coeff2,
    unsigned short* __restrict__ W1f, unsigned short* __restrict__ W2f) {
    int r = blockIdx.x;
    int tid = threadIdx.x;
    float c1[8], c2[8];
#pragma unroll
    for (int b = 0; b < 8; ++b) { c1[b] = coeff1[r * 8 + b]; c2[b] = coeff2[r * 8 + b]; }
    for (int idx = tid; idx < 4096; idx += 256) {
        int j = idx & 7, lane = (idx >> 3) & 63, nt = (idx >> 9) & 3, kt = idx >> 11;
        int i = kt * 32 + ((lane >> 4) << 3) + j;
        int jo = nt * 16 + (lane & 15);
        float s = 0.f;
#pragma unroll
        for (int b = 0; b < 8; ++b) s = fmaf(c1[b], bases1[b * 4096 + i * 64 + jo], s);
        W1f[r * 4096 + idx] = f2bf(s);
    }
    for (int idx = tid; idx < 1024; idx += 256) {
        int j = idx & 7, lane = (idx >> 3) & 63, kt = idx >> 9;
        int i = kt * 32 + ((lane >> 4) << 3) + j;
        int jo = lane & 15;
        float s = 0.f;
#pragma unroll
        for (int b = 0; b < 8; ++b) s = fmaf(c2[b], bases2[b * 1024 + i * 16 + jo], s);
        W2f[r * 1024 + idx] = f2bf(s);
    }
}

// ---- self-loop layer1 + x->bf16 cast fused
__global__ __launch_bounds__(256) void k_lin1x(
    const float* __restrict__ x, const float* __restrict__ wself,
    const float* __restrict__ bias, unsigned short* __restrict__ agg,
    unsigned short* __restrict__ xbf, int nNodes) {
    int lane = threadIdx.x & 63;
    int gw = (int)((blockIdx.x * blockDim.x + threadIdx.x) >> 6);
    int nW = (int)((gridDim.x * blockDim.x) >> 6);
    float w[64];
#pragma unroll
    for (int i = 0; i < 64; ++i) w[i] = wself[i * 64 + lane];
    float bj = bias[lane];
    for (int n = gw; n < nNodes; n += nW) {
        float xv = x[(size_t)n * 64 + lane];
        xbf[(size_t)n * 64 + lane] = f2bf(xv);
        float a0 = 0.f, a1 = 0.f, a2 = 0.f, a3 = 0.f;
#pragma unroll
        for (int i = 0; i < 64; i += 4) {
            a0 = fmaf(bcast(xv, i + 0), w[i + 0], a0);
            a1 = fmaf(bcast(xv, i + 1), w[i + 1], a1);
            a2 = fmaf(bcast(xv, i + 2), w[i + 2], a2);
            a3 = fmaf(bcast(xv, i + 3), w[i + 3], a3);
        }
        agg[(size_t)n * 64 + lane] = f2bf(bj + ((a0 + a1) + (a2 + a3)));
    }
}

// ---- bucket counting sort by dst>>8: per-block LDS int hist
__global__ __launch_bounds__(256) void k_bhist(
    const int* __restrict__ dst, int* __restrict__ bh, int nE, int nBins) {
    __shared__ int h[512];
    for (int i = threadIdx.x; i < 512; i += 256) h[i] = 0;
    __syncthreads();
    int blk = blockIdx.x;
    int ech = (nE + NBLK1 - 1) / NBLK1;
    int e0 = blk * ech, e1 = min(e0 + ech, nE);
    for (int e = e0 + threadIdx.x; e < e1; e += 256)
        atomicAdd(&h[dst[e] >> 8], 1);
    __syncthreads();
    for (int t = threadIdx.x; t < nBins; t += 256) bh[t * NBLK1 + blk] = h[t];
}

// exclusive scan within 256-chunks
__global__ __launch_bounds__(256) void k_scanblk(
    const int* __restrict__ in, int* __restrict__ outx,
    int* __restrict__ btot, int n) {
    __shared__ int sm[256];
    int tid = threadIdx.x;
    int i = blockIdx.x * 256 + tid;
    int d = (i < n) ? in[i] : 0;
    sm[tid] = d;
    __syncthreads();
#pragma unroll
    for (int off = 1; off < 256; off <<= 1) {
        int v = (tid >= off) ? sm[tid - off] : 0;
        __syncthreads();
        sm[tid] += v;
        __syncthreads();
    }
    if (i < n) outx[i] = sm[tid] - d;
    if (tid == 255) btot[blockIdx.x] = sm[255];
}

__global__ void k_scantop(const int* __restrict__ btot, int* __restrict__ boff, int nB) {
    __shared__ int sm[512];
    int t = threadIdx.x;
    int d = (t < nB) ? btot[t] : 0;
    sm[t] = d;
    __syncthreads();
#pragma unroll
    for (int off = 1; off < 512; off <<= 1) {
        int v = (t >= off) ? sm[t - off] : 0;
        __syncthreads();
        sm[t] += v;
        __syncthreads();
    }
    if (t < nB) boff[t] = sm[t] - d;
}

__global__ __launch_bounds__(256) void k_scanadd2(
    int* __restrict__ bhs, const int* __restrict__ boff, int n) {
    int i = blockIdx.x * 256 + threadIdx.x;
    if (i < n) bhs[i] += boff[i >> 8];
}

// scatter payload into bucket order (LDS int cursors, no global atomics)
__global__ __launch_bounds__(256) void k_bscat(
    const int* __restrict__ dst, const int* __restrict__ src,
    const int* __restrict__ et, const int* __restrict__ bhs,
    int* __restrict__ payload, int nE, int nBins) {
    __shared__ int cur[512];
    int blk = blockIdx.x;
    for (int t = threadIdx.x; t < nBins; t += 256) cur[t] = bhs[t * NBLK1 + blk];
    __syncthreads();
    int ech = (nE + NBLK1 - 1) / NBLK1;
    int e0 = blk * ech, e1 = min(e0 + ech, nE);
    for (int e = e0 + threadIdx.x; e < e1; e += 256) {
        int d = dst[e];
        int pos = atomicAdd(&cur[d >> 8], 1);
        payload[pos] = ((src[e] * 8 + et[e]) << 8) | (d & 255);
    }
}

// per-bucket refine: payload (bucket-sorted) -> per-node CSR (skey, nodeoff)
// two passes over the bucket, LDS int atomics only, sequential global writes
__global__ __launch_bounds__(256) void k_brefine(
    const int* __restrict__ payload, const int* __restrict__ bhs,
    int* __restrict__ skey, int* __restrict__ nodeoff,
    int nE, int nBins, int nNodes) {
    __shared__ int h[256];
    __shared__ int cur[256];
    __shared__ int sm[256];
    int b = blockIdx.x;
    int e0 = bhs[b * NBLK1];
    int e1 = (b + 1 < nBins) ? bhs[(b + 1) * NBLK1] : nE;
    int t = threadIdx.x;
    h[t] = 0;
    __syncthreads();
    for (int e = e0 + t; e < e1; e += 256)
        atomicAdd(&h[payload[e] & 255], 1);
    __syncthreads();
    int d = h[t];
    sm[t] = d;
    __syncthreads();
#pragma unroll
    for (int off = 1; off < 256; off <<= 1) {
        int v = (t >= off) ? sm[t - off] : 0;
        __syncthreads();
        sm[t] += v;
        __syncthreads();
    }
    int excl = sm[t] - d;
    cur[t] = excl;
    int n = (b << 8) + t;
    if (n < nNodes) nodeoff[n] = e0 + excl;
    __syncthreads();
    for (int e = e0 + t; e < e1; e += 256) {
        int pay = payload[e];
        int pos = atomicAdd(&cur[pay & 255], 1);
        skey[e0 + pos] = pay >> 8;
    }
    if (b == 0 && t == 0) nodeoff[nNodes] = nE;
}

// ---- xw1[(n*8+r)*64] = bf16( x[n] @ W_r )  (dense MFMA)
__global__ __launch_bounds__(256) void k_xw1(
    const unsigned short* __restrict__ xbf,
    const unsigned short* __restrict__ W1f,
    unsigned short* __restrict__ xw1, int nNodes) {
    __shared__ unsigned lds[4][16 * 36];
    int lane = threadIdx.x & 63;
    int wid = (int)(threadIdx.x >> 6);
    int tile = blockIdx.x * 4 + wid;
    int n0 = tile * 16;
    if (n0 >= nNodes) return;
    int sA = n0 + (lane & 15);
    if (sA >= nNodes) sA = nNodes - 1;
    const unsigned short* xrow = xbf + (size_t)sA * 64 + ((lane >> 4) << 3);
    bf16x8 a[2];
    a[0] = *(const bf16x8*)(xrow);
    a[1] = *(const bf16x8*)(xrow + 32);
    unsigned* L = lds[wid];
    const int even = !(lane & 1);
    const int cpair = (lane & 14) >> 1;
    int row2 = lane >> 2, ch = lane & 3;
    int nOut = n0 + row2;
    for (int r = 0; r < 8; ++r) {
        const unsigned short* Wf = W1f + r * 4096;
        f32x4 z = {0.f, 0.f, 0.f, 0.f};
        f32x4 acc[4] = {z, z, z, z};
#pragma unroll
        for (int kt = 0; kt < 2; ++kt)
#pragma unroll
            for (int nt = 0; nt < 4; ++nt) {
                bf16x8 b = *(const bf16x8*)(Wf + (kt * 4 + nt) * 512 + lane * 8);
                acc[nt] = __builtin_amdgcn_mfma_f32_16x16x32_bf16(a[kt], b, acc[nt], 0, 0, 0);
            }
#pragma unroll
        for (int reg = 0; reg < 4; ++reg) {
            int row = ((lane >> 4) << 2) + reg;
#pragma unroll
            for (int nt = 0; nt < 4; ++nt) {
                float mine = acc[nt][reg];
                float oth = __shfl_xor(mine, 1, 64);
                unsigned pk = even ? ((unsigned)f2bf(mine) | ((unsigned)f2bf(oth) << 16))
                                   : ((unsigned)f2bf(oth) | ((unsigned)f2bf(mine) << 16));
                if (even ? (nt < 2) : (nt >= 2)) L[row * 36 + cpair + nt * 8] = pk;
            }
        }
        if (nOut < nNodes) {
            uint4 v0 = *(uint4*)&L[row2 * 36 + ch * 4];
            uint4 v1 = *(uint4*)&L[row2 * 36 + 16 + ch * 4];
            uint4* mp = (uint4*)(xw1 + ((size_t)nOut * 8 + r) * 64);
            mp[ch] = v0;
            mp[4 + ch] = v1;
        }
    }
}

// ---- fused gather + segment sum, layer1 (16-lane group/node, uint2/lane)
__global__ __launch_bounds__(256) void k_seg1f(
    const unsigned short* __restrict__ xw1, const int* __restrict__ skey,
    const int* __restrict__ nodeoff, unsigned short* __restrict__ agg1,
    int nNodes) {
    int gl = threadIdx.x & 15;                 // 4 cols per lane
    int grp = (int)((blockIdx.x * blockDim.x + threadIdx.x) >> 4);
    int nG = (int)((gridDim.x * blockDim.x) >> 4);
    for (int n = grp; n < nNodes; n += nG) {
        int s0 = nodeoff[n], s1 = nodeoff[n + 1];
        uint2 v = *(const uint2*)(agg1 + (size_t)n * 64 + gl * 4);
        float a0 = bf2f((unsigned short)v.x), a1 = bf2f((unsigned short)(v.x >> 16));
        float a2 = bf2f((unsigned short)v.y), a3 = bf2f((unsigned short)(v.y >> 16));
        for (int i = s0; i < s1; ++i) {
            int key = skey[i];
            uint2 m = *(const uint2*)(xw1 + (size_t)key * 64 + gl * 4);
            a0 += bf2f((unsigned short)m.x); a1 += bf2f((unsigned short)(m.x >> 16));
            a2 += bf2f((unsigned short)m.y); a3 += bf2f((unsigned short)(m.y >> 16));
        }
        uint2 p;
        p.x = (unsigned)f2bf(a0) | ((unsigned)f2bf(a1) << 16);
        p.y = (unsigned)f2bf(a2) | ((unsigned)f2bf(a3) << 16);
        *(uint2*)(agg1 + (size_t)n * 64 + gl * 4) = p;
    }
}

// ---- relu (in-place) + self-loop layer2 -> agg2 init
__global__ __launch_bounds__(256) void k_lin2(
    unsigned short* __restrict__ agg1, const float* __restrict__ wself,
    const float* __restrict__ bias, unsigned short* __restrict__ agg2, int nNodes) {
    int lane = threadIdx.x & 63;
    int j = lane & 15;
    int gw = (int)((blockIdx.x * blockDim.x + threadIdx.x) >> 6);
    int nW = (int)((gridDim.x * blockDim.x) >> 6);
    float w[64];
#pragma unroll
    for (int i = 0; i < 64; ++i) w[i] = wself[i * 16 + j];
    float bj = bias[j];
    for (int n = gw; n < nNodes; n += nW) {
        unsigned short raw = agg1[(size_t)n * 64 + lane];
        unsigned short rbf = (raw & 0x8000u) ? (unsigned short)0 : raw;
        agg1[(size_t)n * 64 + lane] = rbf;          // h in place
        float hv = bf2f(rbf);
        float a0 = 0.f, a1 = 0.f, a2 = 0.f, a3 = 0.f;
#pragma unroll
        for (int i = 0; i < 64; i += 4) {
            a0 = fmaf(bcast(hv, i + 0), w[i + 0], a0);
            a1 = fmaf(bcast(hv, i + 1), w[i + 1], a1);
            a2 = fmaf(bcast(hv, i + 2), w[i + 2], a2);
            a3 = fmaf(bcast(hv, i + 3), w[i + 3], a3);
        }
        if (lane < 16) agg2[(size_t)n * 16 + lane] = f2bf(bj + ((a0 + a1) + (a2 + a3)));
    }
}

// ---- xw2[(n*8+r)*16] = bf16( h[n] @ W2_r )
__global__ __launch_bounds__(256) void k_xw2(
    const unsigned short* __restrict__ h,
    const unsigned short* __restrict__ W2f,
    unsigned short* __restrict__ xw2, int nNodes) {
    __shared__ unsigned lds[4][16 * 12];
    int lane = threadIdx.x & 63;
    int wid = (int)(threadIdx.x >> 6);
    int tile = blockIdx.x * 4 + wid;
    int n0 = tile * 16;
    if (n0 >= nNodes) return;
    int sA = n0 + (lane & 15);
    if (sA >= nNodes) sA = nNodes - 1;
    const unsigned short* hrow = h + (size_t)sA * 64 + ((lane >> 4) << 3);
    bf16x8 a[2];
    a[0] = *(const bf16x8*)(hrow);
    a[1] = *(const bf16x8*)(hrow + 32);
    unsigned* L = lds[wid];
    const int even = !(lane & 1);
    const int cpair = (lane & 14) >> 1;
    int row2 = lane >> 1, ch = lane & 1;
    int nOut = n0 + row2;
    for (int r = 0; r < 8; ++r) {
        const unsigned short* Wf = W2f + r * 1024;
        bf16x8 b0 = *(const bf16x8*)(Wf + lane * 8);
        bf16x8 b1 = *(const bf16x8*)(Wf + 512 + lane * 8);
        f32x4 acc = {0.f, 0.f, 0.f, 0.f};
        acc = __builtin_amdgcn_mfma_f32_16x16x32_bf16(a[0], b0, acc, 0, 0, 0);
        acc = __builtin_amdgcn_mfma_f32_16x16x32_bf16(a[1], b1, acc, 0, 0, 0);
#pragma unroll
        for (int reg = 0; reg < 4; ++reg) {
            int row = ((lane >> 4) << 2) + reg;
            float mine = acc[reg];
            float oth = __shfl_xor(mine, 1, 64);
            unsigned pk = even ? ((unsigned)f2bf(mine) | ((unsigned)f2bf(oth) << 16))
                               : ((unsigned)f2bf(oth) | ((unsigned)f2bf(mine) << 16));
            if (even ? (reg < 2) : (reg >= 2)) L[row * 12 + cpair] = pk;
        }
        if (lane < 32 && nOut < nNodes) {
            uint4 v = *(uint4*)&L[row2 * 12 + ch * 4];
            ((uint4*)(xw2 + ((size_t)nOut * 8 + r) * 16))[ch] = v;
        }
    }
}

// ---- fused gather + segment sum, layer2 (4-lane group/node, uint2/lane)
__global__ __launch_bounds__(256) void k_seg2f(
    const unsigned short* __restrict__ xw2, const int* __restrict__ skey,
    const int* __restrict__ nodeoff, unsigned short* __restrict__ agg2,
    int nNodes) {
    int gl = threadIdx.x & 3;                  // 4 cols per lane
    int grp = (int)((blockIdx.x * blockDim.x + threadIdx.x) >> 2);
    int nG = (int)((gridDim.x * blockDim.x) >> 2);
    for (int n = grp; n < nNodes; n += nG) {
        int s0 = nodeoff[n], s1 = nodeoff[n + 1];
        uint2 v = *(const uint2*)(agg2 + (size_t)n * 16 + gl * 4);
        float a0 = bf2f((unsigned short)v.x), a1 = bf2f((unsigned short)(v.x >> 16));
        float a2 = bf2f((unsigned short)v.y), a3 = bf2f((unsigned short)(v.y >> 16));
        for (int i = s0; i < s1; ++i) {
            int key = skey[i];
            uint2 m = *(const uint2*)(xw2 + (size_t)key * 16 + gl * 4);
            a0 += bf2f((unsigned short)m.x); a1 += bf2f((unsigned short)(m.x >> 16));
            a2 += bf2f((unsigned short)m.y); a3 += bf2f((unsigned short)(m.y >> 16));
        }
        uint2 p;
        p.x = (unsigned)f2bf(a0) | ((unsigned)f2bf(a1) << 16);
        p.y = (unsigned)f2bf(a2) | ((unsigned)f2bf(a3) << 16);
        *(uint2*)(agg2 + (size_t)n * 16 + gl * 4) = p;
    }
}

__global__ void k_bounds(const int* __restrict__ gid, int* __restrict__ start, int nNodes) {
    int t = blockIdx.x * blockDim.x + threadIdx.x;
    if (t > 64) return;
    int lo = 0, hi = nNodes;
    while (lo < hi) {
        int mid = (lo + hi) >> 1;
        if (gid[mid] < t) lo = mid + 1; else hi = mid;
    }
    start[t] = lo;
}

__global__ __launch_bounds__(256) void k_pool(
    const unsigned short* __restrict__ agg2, const int* __restrict__ start,
    float* __restrict__ out) {
    __shared__ float sm[256];
    int g = blockIdx.x;
    int t = threadIdx.x;
    int c = t & 15, idx = t >> 4;
    int s0 = start[g], s1 = start[g + 1];
    float acc = 0.f;
    for (int n = s0 + idx; n < s1; n += 16) acc += fmaxf(bf2f(agg2[(size_t)n * 16 + c]), 0.f);
    sm[t] = acc;
    __syncthreads();
#pragma unroll
    for (int off = 128; off >= 16; off >>= 1) {
        if (t < off) sm[t] += sm[t + off];
        __syncthreads();
    }
    if (t < 16) {
        float cnt = (float)(s1 - s0);
        out[g * 16 + t] = sm[t] / fmaxf(cnt, 1.f);
    }
}

extern "C" void kernel_launch(void* const* d_in, const int* in_sizes, int n_in,
                              void* d_out, int out_size, void* d_ws, size_t ws_size,
                              hipStream_t stream) {
    const float* x      = (const float*)d_in[0];
    const int*   src    = (const int*)d_in[1];
    const int*   dst    = (const int*)d_in[2];
    const int*   et     = (const int*)d_in[3];
    const int*   gid    = (const int*)d_in[4];
    const float* bases1 = (const float*)d_in[5];
    const float* coeff1 = (const float*)d_in[6];
    const float* wself1 = (const float*)d_in[7];
    const float* bias1  = (const float*)d_in[8];
    const float* bases2 = (const float*)d_in[9];
    const float* coeff2 = (const float*)d_in[10];
    const float* wself2 = (const float*)d_in[11];
    const float* bias2  = (const float*)d_in[12];
    float* out = (float*)d_out;

    int nNodes = in_sizes[0] / 64;
    int nE = in_sizes[1];
    int nBins = (nNodes + 255) >> 8;
    int nBh = nBins * NBLK1;

    char* ws = (char*)d_ws;
    unsigned short* W1f  = (unsigned short*)(ws);
    unsigned short* W2f  = (unsigned short*)(ws + 65536);
    unsigned short* xbf  = (unsigned short*)(ws + 81920);
    unsigned short* agg1 = (unsigned short*)(ws + 12881920);
    unsigned short* agg2 = (unsigned short*)(ws + 25681920);
    int*   payload = (int*)(ws + 28881920);
    int*   skey    = (int*)(ws + 32881920);
    int*   nodeoff = (int*)(ws + 36881920);
    int*   bh      = (int*)(ws + 37282048);
    int*   bhs     = (int*)(ws + 37482240);
    int*   btot    = (int*)(ws + 37682432);
    int*   boff    = (int*)(ws + 37684480);
    int*   start   = (int*)(ws + 37686528);
    unsigned short* xw1 = (unsigned short*)(ws + 37687040);
    unsigned short* xw2 = xw1;   // layer-2 reuses xw1 space

    int tiles = (nNodes + 15) / 16;
    int xwb = (tiles + 3) / 4;
    int scb = (nBh + 255) / 256;

    hipLaunchKernelGGL(k_weights, dim3(8), dim3(256), 0, stream,
                       bases1, coeff1, bases2, coeff2, W1f, W2f);
    hipLaunchKernelGGL(k_lin1x, dim3(512), dim3(256), 0, stream,
                       x, wself1, bias1, agg1, xbf, nNodes);
    hipLaunchKernelGGL(k_bhist, dim3(NBLK1), dim3(256), 0, stream,
                       dst, bh, nE, nBins);
    hipLaunchKernelGGL(k_scanblk, dim3(scb), dim3(256), 0, stream,
                       bh, bhs, btot, nBh);
    hipLaunchKernelGGL(k_scantop, dim3(1), dim3(512), 0, stream, btot, boff, scb);
    hipLaunchKernelGGL(k_scanadd2, dim3(scb), dim3(256), 0, stream,
                       bhs, boff, nBh);
    hipLaunchKernelGGL(k_bscat, dim3(NBLK1), dim3(256), 0, stream,
                       dst, src, et, bhs, payload, nE, nBins);
    hipLaunchKernelGGL(k_brefine, dim3(nBins), dim3(256), 0, stream,
                       payload, bhs, skey, nodeoff, nE, nBins, nNodes);
    hipLaunchKernelGGL(k_xw1, dim3(xwb), dim3(256), 0, stream,
                       xbf, W1f, xw1, nNodes);
    hipLaunchKernelGGL(k_seg1f, dim3(2048), dim3(256), 0, stream,
                       xw1, skey, nodeoff, agg1, nNodes);
    hipLaunchKernelGGL(k_lin2, dim3(512), dim3(256), 0, stream,
                       agg1, wself2, bias2, agg2, nNodes);
    hipLaunchKernelGGL(k_xw2, dim3(xwb), dim3(256), 0, stream,
                       agg1, W2f, xw2, nNodes);
    hipLaunchKernelGGL(k_seg2f, dim3(1024), dim3(256), 0, stream,
                       xw2, skey, nodeoff, agg2, nNodes);
    hipLaunchKernelGGL(k_bounds, dim3(1), dim3(128), 0, stream, gid, start, nNodes);
    hipLaunchKernelGGL(k_pool, dim3(64), dim3(256), 0, stream, agg2, start, out);
}

// Round 11
// 211.573 us; speedup vs baseline: 3.5485x; 1.3179x over previous
//
#include <hip/hip_runtime.h>

// ---------------------------------------------------------------------------
// RGCN (basis decomposition, 2 layers) + mean-pool.  v11 = v10 plus:
//  - self-loop GEMVs folded into the MFMA xw kernels as a 9th "relation"
//    (r=8 uses wself frags + bias, writes agg init rows); k_lin1x/k_lin2
//    deleted; ReLU moved into seg1f epilogue; only a cast kernel remains.
//  - seg1f: 8-lane groups x uint4 (16B/lane); seg2f: 2-lane groups x uint4.
//
// ws layout (bytes):
//   W1f     us[8*4096]     @ 0          B-frags of W1 (bf16)
//   W2f     us[8*1024]     @ 65536
//   W1sf    us[4096]       @ 81920      wself1 frags
//   W2sf    us[1024]       @ 90112      wself2 frags
//   xbf     us[N*64]       @ 92160      x in bf16
//   agg1    us[N*64]       @ 12892160   layer-1 agg (becomes h)
//   agg2    us[N*16]       @ 25692160   layer-2 agg
//   payload int[E]         @ 28892160   (src*8+et)<<8 | dst&255
//   skey    int[E]         @ 32892160   src*8+et, dst-sorted
//   nodeoff int[N+1]       @ 36892160
//   bh      int[nBins*128] @ 37292224
//   bhs     int[nBins*128] @ 37492416
//   btot    int[512]       @ 37692608
//   boff    int[512]       @ 37694656
//   start   int[65]        @ 37696704
//   xw1     us[N*8*64]     @ 37697024   (102.4 MB; xw2 aliases)
// NEED ~140.1 MB (ws proven >= 166 MB in rounds 5-8)
// ---------------------------------------------------------------------------

typedef __attribute__((ext_vector_type(8))) short bf16x8;
typedef __attribute__((ext_vector_type(4))) float f32x4;

#define NBLK1 128   // blocks for bucket counting sort

__device__ __forceinline__ unsigned short f2bf(float f) {
    unsigned u = __float_as_uint(f);
    unsigned r = u + 0x7FFFu + ((u >> 16) & 1u);   // RNE
    return (unsigned short)(r >> 16);
}

__device__ __forceinline__ float bf2f(unsigned short u) {
    return __uint_as_float(((unsigned)u) << 16);
}

// ---- weights in B-fragment order (16x16x32 bf16): lane l holds
// B[k = kt*32+(l>>4)*8+j][n = nt*16+(l&15)], j=0..7.  Also emits wself frags.
__global__ __launch_bounds__(256) void k_weights(
    const float* __restrict__ bases1, const float* __restrict__ coeff1,
    const float* __restrict__ bases2, const float* __restrict__ coeff2,
    const float* __restrict__ wself1, const float* __restrict__ wself2,
    unsigned short* __restrict__ W1f, unsigned short* __restrict__ W2f,
    unsigned short* __restrict__ W1sf, unsigned short* __restrict__ W2sf) {
    int r = blockIdx.x;
    int tid = threadIdx.x;
    float c1[8], c2[8];
#pragma unroll
    for (int b = 0; b < 8; ++b) { c1[b] = coeff1[r * 8 + b]; c2[b] = coeff2[r * 8 + b]; }
    for (int idx = tid; idx < 4096; idx += 256) {
        int j = idx & 7, lane = (idx >> 3) & 63, nt = (idx >> 9) & 3, kt = idx >> 11;
        int i = kt * 32 + ((lane >> 4) << 3) + j;
        int jo = nt * 16 + (lane & 15);
        float s = 0.f;
#pragma unroll
        for (int b = 0; b < 8; ++b) s = fmaf(c1[b], bases1[b * 4096 + i * 64 + jo], s);
        W1f[r * 4096 + idx] = f2bf(s);
        if (r == 0) W1sf[idx] = f2bf(wself1[i * 64 + jo]);
    }
    for (int idx = tid; idx < 1024; idx += 256) {
        int j = idx & 7, lane = (idx >> 3) & 63, kt = idx >> 9;
        int i = kt * 32 + ((lane >> 4) << 3) + j;
        int jo = lane & 15;
        float s = 0.f;
#pragma unroll
        for (int b = 0; b < 8; ++b) s = fmaf(c2[b], bases2[b * 1024 + i * 16 + jo], s);
        W2f[r * 1024 + idx] = f2bf(s);
        if (r == 0) W2sf[idx] = f2bf(wself2[i * 16 + jo]);
    }
}

// ---- x -> bf16 cast (vectorized)
__global__ __launch_bounds__(256) void k_cast(
    const float* __restrict__ x, unsigned short* __restrict__ xbf, int n8) {
    int stride = gridDim.x * blockDim.x;
    for (int i = blockIdx.x * blockDim.x + threadIdx.x; i < n8; i += stride) {
        f32x4 u0 = *(const f32x4*)(x + (size_t)i * 8);
        f32x4 u1 = *(const f32x4*)(x + (size_t)i * 8 + 4);
        bf16x8 t;
        t[0] = (short)f2bf(u0[0]); t[1] = (short)f2bf(u0[1]);
        t[2] = (short)f2bf(u0[2]); t[3] = (short)f2bf(u0[3]);
        t[4] = (short)f2bf(u1[0]); t[5] = (short)f2bf(u1[1]);
        t[6] = (short)f2bf(u1[2]); t[7] = (short)f2bf(u1[3]);
        *(bf16x8*)(xbf + (size_t)i * 8) = t;
    }
}

// ---- bucket counting sort by dst>>8: per-block LDS int hist
__global__ __launch_bounds__(256) void k_bhist(
    const int* __restrict__ dst, int* __restrict__ bh, int nE, int nBins) {
    __shared__ int h[512];
    for (int i = threadIdx.x; i < 512; i += 256) h[i] = 0;
    __syncthreads();
    int blk = blockIdx.x;
    int ech = (nE + NBLK1 - 1) / NBLK1;
    int e0 = blk * ech, e1 = min(e0 + ech, nE);
    for (int e = e0 + threadIdx.x; e < e1; e += 256)
        atomicAdd(&h[dst[e] >> 8], 1);
    __syncthreads();
    for (int t = threadIdx.x; t < nBins; t += 256) bh[t * NBLK1 + blk] = h[t];
}

__global__ __launch_bounds__(256) void k_scanblk(
    const int* __restrict__ in, int* __restrict__ outx,
    int* __restrict__ btot, int n) {
    __shared__ int sm[256];
    int tid = threadIdx.x;
    int i = blockIdx.x * 256 + tid;
    int d = (i < n) ? in[i] : 0;
    sm[tid] = d;
    __syncthreads();
#pragma unroll
    for (int off = 1; off < 256; off <<= 1) {
        int v = (tid >= off) ? sm[tid - off] : 0;
        __syncthreads();
        sm[tid] += v;
        __syncthreads();
    }
    if (i < n) outx[i] = sm[tid] - d;
    if (tid == 255) btot[blockIdx.x] = sm[255];
}

__global__ void k_scantop(const int* __restrict__ btot, int* __restrict__ boff, int nB) {
    __shared__ int sm[512];
    int t = threadIdx.x;
    int d = (t < nB) ? btot[t] : 0;
    sm[t] = d;
    __syncthreads();
#pragma unroll
    for (int off = 1; off < 512; off <<= 1) {
        int v = (t >= off) ? sm[t - off] : 0;
        __syncthreads();
        sm[t] += v;
        __syncthreads();
    }
    if (t < nB) boff[t] = sm[t] - d;
}

__global__ __launch_bounds__(256) void k_scanadd2(
    int* __restrict__ bhs, const int* __restrict__ boff, int n) {
    int i = blockIdx.x * 256 + threadIdx.x;
    if (i < n) bhs[i] += boff[i >> 8];
}

// scatter payload into bucket order (LDS int cursors)
__global__ __launch_bounds__(256) void k_bscat(
    const int* __restrict__ dst, const int* __restrict__ src,
    const int* __restrict__ et, const int* __restrict__ bhs,
    int* __restrict__ payload, int nE, int nBins) {
    __shared__ int cur[512];
    int blk = blockIdx.x;
    for (int t = threadIdx.x; t < nBins; t += 256) cur[t] = bhs[t * NBLK1 + blk];
    __syncthreads();
    int ech = (nE + NBLK1 - 1) / NBLK1;
    int e0 = blk * ech, e1 = min(e0 + ech, nE);
    for (int e = e0 + threadIdx.x; e < e1; e += 256) {
        int d = dst[e];
        int pos = atomicAdd(&cur[d >> 8], 1);
        payload[pos] = ((src[e] * 8 + et[e]) << 8) | (d & 255);
    }
}

// per-bucket refine -> per-node CSR (skey, nodeoff)
__global__ __launch_bounds__(256) void k_brefine(
    const int* __restrict__ payload, const int* __restrict__ bhs,
    int* __restrict__ skey, int* __restrict__ nodeoff,
    int nE, int nBins, int nNodes) {
    __shared__ int h[256];
    __shared__ int cur[256];
    __shared__ int sm[256];
    int b = blockIdx.x;
    int e0 = bhs[b * NBLK1];
    int e1 = (b + 1 < nBins) ? bhs[(b + 1) * NBLK1] : nE;
    int t = threadIdx.x;
    h[t] = 0;
    __syncthreads();
    for (int e = e0 + t; e < e1; e += 256)
        atomicAdd(&h[payload[e] & 255], 1);
    __syncthreads();
    int d = h[t];
    sm[t] = d;
    __syncthreads();
#pragma unroll
    for (int off = 1; off < 256; off <<= 1) {
        int v = (t >= off) ? sm[t - off] : 0;
        __syncthreads();
        sm[t] += v;
        __syncthreads();
    }
    int excl = sm[t] - d;
    cur[t] = excl;
    int n = (b << 8) + t;
    if (n < nNodes) nodeoff[n] = e0 + excl;
    __syncthreads();
    for (int e = e0 + t; e < e1; e += 256) {
        int pay = payload[e];
        int pos = atomicAdd(&cur[pay & 255], 1);
        skey[e0 + pos] = pay >> 8;
    }
    if (b == 0 && t == 0) nodeoff[nNodes] = nE;
}

// ---- xw1[(n*8+r)*64] = bf16( x[n] @ W_r ), r=0..7;
//      r=8: agg1[n*64] = bf16( x[n] @ wself1 + bias1 )   (dense MFMA)
__global__ __launch_bounds__(256) void k_xw1(
    const unsigned short* __restrict__ xbf,
    const unsigned short* __restrict__ W1f,
    const unsigned short* __restrict__ W1sf,
    const float* __restrict__ bias1,
    unsigned short* __restrict__ xw1, unsigned short* __restrict__ agg1,
    int nNodes) {
    __shared__ unsigned lds[4][16 * 36];
    int lane = threadIdx.x & 63;
    int wid = (int)(threadIdx.x >> 6);
    int tile = blockIdx.x * 4 + wid;
    int n0 = tile * 16;
    if (n0 >= nNodes) return;
    int sA = n0 + (lane & 15);
    if (sA >= nNodes) sA = nNodes - 1;
    const unsigned short* xrow = xbf + (size_t)sA * 64 + ((lane >> 4) << 3);
    bf16x8 a[2];
    a[0] = *(const bf16x8*)(xrow);
    a[1] = *(const bf16x8*)(xrow + 32);
    float bj[4];
#pragma unroll
    for (int nt = 0; nt < 4; ++nt) bj[nt] = bias1[nt * 16 + (lane & 15)];
    unsigned* L = lds[wid];
    const int even = !(lane & 1);
    const int cpair = (lane & 14) >> 1;
    int row2 = lane >> 2, ch = lane & 3;
    int nOut = n0 + row2;
    for (int r = 0; r < 9; ++r) {
        const unsigned short* Wf = (r < 8) ? (W1f + r * 4096) : W1sf;
        f32x4 z = {0.f, 0.f, 0.f, 0.f};
        f32x4 acc[4] = {z, z, z, z};
#pragma unroll
        for (int kt = 0; kt < 2; ++kt)
#pragma unroll
            for (int nt = 0; nt < 4; ++nt) {
                bf16x8 b = *(const bf16x8*)(Wf + (kt * 4 + nt) * 512 + lane * 8);
                acc[nt] = __builtin_amdgcn_mfma_f32_16x16x32_bf16(a[kt], b, acc[nt], 0, 0, 0);
            }
        if (r == 8) {
#pragma unroll
            for (int nt = 0; nt < 4; ++nt)
#pragma unroll
                for (int reg = 0; reg < 4; ++reg) acc[nt][reg] += bj[nt];
        }
#pragma unroll
        for (int reg = 0; reg < 4; ++reg) {
            int row = ((lane >> 4) << 2) + reg;
#pragma unroll
            for (int nt = 0; nt < 4; ++nt) {
                float mine = acc[nt][reg];
                float oth = __shfl_xor(mine, 1, 64);
                unsigned pk = even ? ((unsigned)f2bf(mine) | ((unsigned)f2bf(oth) << 16))
                                   : ((unsigned)f2bf(oth) | ((unsigned)f2bf(mine) << 16));
                if (even ? (nt < 2) : (nt >= 2)) L[row * 36 + cpair + nt * 8] = pk;
            }
        }
        if (nOut < nNodes) {
            uint4 v0 = *(uint4*)&L[row2 * 36 + ch * 4];
            uint4 v1 = *(uint4*)&L[row2 * 36 + 16 + ch * 4];
            uint4* mp = (r < 8) ? (uint4*)(xw1 + ((size_t)nOut * 8 + r) * 64)
                                : (uint4*)(agg1 + (size_t)nOut * 64);
            mp[ch] = v0;
            mp[4 + ch] = v1;
        }
    }
}

// ---- fused gather + segment sum + relu, layer1 (8-lane group, uint4/lane)
__global__ __launch_bounds__(256) void k_seg1f(
    const unsigned short* __restrict__ xw1, const int* __restrict__ skey,
    const int* __restrict__ nodeoff, unsigned short* __restrict__ agg1,
    int nNodes) {
    int gl = threadIdx.x & 7;                  // 8 cols per lane
    int grp = (int)((blockIdx.x * blockDim.x + threadIdx.x) >> 3);
    int nG = (int)((gridDim.x * blockDim.x) >> 3);
    for (int n = grp; n < nNodes; n += nG) {
        int s0 = nodeoff[n], s1 = nodeoff[n + 1];
        uint4 v = *(const uint4*)(agg1 + (size_t)n * 64 + gl * 8);
        float a0 = bf2f((unsigned short)v.x), a1 = bf2f((unsigned short)(v.x >> 16));
        float a2 = bf2f((unsigned short)v.y), a3 = bf2f((unsigned short)(v.y >> 16));
        float a4 = bf2f((unsigned short)v.z), a5 = bf2f((unsigned short)(v.z >> 16));
        float a6 = bf2f((unsigned short)v.w), a7 = bf2f((unsigned short)(v.w >> 16));
        for (int i = s0; i < s1; ++i) {
            int key = skey[i];
            uint4 m = *(const uint4*)(xw1 + (size_t)key * 64 + gl * 8);
            a0 += bf2f((unsigned short)m.x); a1 += bf2f((unsigned short)(m.x >> 16));
            a2 += bf2f((unsigned short)m.y); a3 += bf2f((unsigned short)(m.y >> 16));
            a4 += bf2f((unsigned short)m.z); a5 += bf2f((unsigned short)(m.z >> 16));
            a6 += bf2f((unsigned short)m.w); a7 += bf2f((unsigned short)(m.w >> 16));
        }
        // relu (h for layer 2)
        a0 = fmaxf(a0, 0.f); a1 = fmaxf(a1, 0.f); a2 = fmaxf(a2, 0.f);
        a3 = fmaxf(a3, 0.f); a4 = fmaxf(a4, 0.f); a5 = fmaxf(a5, 0.f);
        a6 = fmaxf(a6, 0.f); a7 = fmaxf(a7, 0.f);
        uint4 p;
        p.x = (unsigned)f2bf(a0) | ((unsigned)f2bf(a1) << 16);
        p.y = (unsigned)f2bf(a2) | ((unsigned)f2bf(a3) << 16);
        p.z = (unsigned)f2bf(a4) | ((unsigned)f2bf(a5) << 16);
        p.w = (unsigned)f2bf(a6) | ((unsigned)f2bf(a7) << 16);
        *(uint4*)(agg1 + (size_t)n * 64 + gl * 8) = p;
    }
}

// ---- xw2[(n*8+r)*16] = bf16( h[n] @ W2_r ), r=0..7;
//      r=8: agg2[n*16] = bf16( h[n] @ wself2 + bias2 )
__global__ __launch_bounds__(256) void k_xw2(
    const unsigned short* __restrict__ h,
    const unsigned short* __restrict__ W2f,
    const unsigned short* __restrict__ W2sf,
    const float* __restrict__ bias2,
    unsigned short* __restrict__ xw2, unsigned short* __restrict__ agg2,
    int nNodes) {
    __shared__ unsigned lds[4][16 * 12];
    int lane = threadIdx.x & 63;
    int wid = (int)(threadIdx.x >> 6);
    int tile = blockIdx.x * 4 + wid;
    int n0 = tile * 16;
    if (n0 >= nNodes) return;
    int sA = n0 + (lane & 15);
    if (sA >= nNodes) sA = nNodes - 1;
    const unsigned short* hrow = h + (size_t)sA * 64 + ((lane >> 4) << 3);
    bf16x8 a[2];
    a[0] = *(const bf16x8*)(hrow);
    a[1] = *(const bf16x8*)(hrow + 32);
    float bj = bias2[lane & 15];
    unsigned* L = lds[wid];
    const int even = !(lane & 1);
    const int cpair = (lane & 14) >> 1;
    int row2 = lane >> 1, ch = lane & 1;
    int nOut = n0 + row2;
    for (int r = 0; r < 9; ++r) {
        const unsigned short* Wf = (r < 8) ? (W2f + r * 1024) : W2sf;
        bf16x8 b0 = *(const bf16x8*)(Wf + lane * 8);
        bf16x8 b1 = *(const bf16x8*)(Wf + 512 + lane * 8);
        f32x4 acc = {0.f, 0.f, 0.f, 0.f};
        acc = __builtin_amdgcn_mfma_f32_16x16x32_bf16(a[0], b0, acc, 0, 0, 0);
        acc = __builtin_amdgcn_mfma_f32_16x16x32_bf16(a[1], b1, acc, 0, 0, 0);
        if (r == 8) {
#pragma unroll
            for (int reg = 0; reg < 4; ++reg) acc[reg] += bj;
        }
#pragma unroll
        for (int reg = 0; reg < 4; ++reg) {
            int row = ((lane >> 4) << 2) + reg;
            float mine = acc[reg];
            float oth = __shfl_xor(mine, 1, 64);
            unsigned pk = even ? ((unsigned)f2bf(mine) | ((unsigned)f2bf(oth) << 16))
                               : ((unsigned)f2bf(oth) | ((unsigned)f2bf(mine) << 16));
            if (even ? (reg < 2) : (reg >= 2)) L[row * 12 + cpair] = pk;
        }
        if (lane < 32 && nOut < nNodes) {
            uint4 v = *(uint4*)&L[row2 * 12 + ch * 4];
            uint4* mp = (r < 8) ? (uint4*)(xw2 + ((size_t)nOut * 8 + r) * 16)
                                : (uint4*)(agg2 + (size_t)nOut * 16);
            mp[ch] = v;
        }
    }
}

// ---- fused gather + segment sum, layer2 (2-lane group, uint4/lane)
__global__ __launch_bounds__(256) void k_seg2f(
    const unsigned short* __restrict__ xw2, const int* __restrict__ skey,
    const int* __restrict__ nodeoff, unsigned short* __restrict__ agg2,
    int nNodes) {
    int gl = threadIdx.x & 1;                  // 8 cols per lane
    int grp = (int)((blockIdx.x * blockDim.x + threadIdx.x) >> 1);
    int nG = (int)((gridDim.x * blockDim.x) >> 1);
    for (int n = grp; n < nNodes; n += nG) {
        int s0 = nodeoff[n], s1 = nodeoff[n + 1];
        uint4 v = *(const uint4*)(agg2 + (size_t)n * 16 + gl * 8);
        float a0 = bf2f((unsigned short)v.x), a1 = bf2f((unsigned short)(v.x >> 16));
        float a2 = bf2f((unsigned short)v.y), a3 = bf2f((unsigned short)(v.y >> 16));
        float a4 = bf2f((unsigned short)v.z), a5 = bf2f((unsigned short)(v.z >> 16));
        float a6 = bf2f((unsigned short)v.w), a7 = bf2f((unsigned short)(v.w >> 16));
        for (int i = s0; i < s1; ++i) {
            int key = skey[i];
            uint4 m = *(const uint4*)(xw2 + (size_t)key * 16 + gl * 8);
            a0 += bf2f((unsigned short)m.x); a1 += bf2f((unsigned short)(m.x >> 16));
            a2 += bf2f((unsigned short)m.y); a3 += bf2f((unsigned short)(m.y >> 16));
            a4 += bf2f((unsigned short)m.z); a5 += bf2f((unsigned short)(m.z >> 16));
            a6 += bf2f((unsigned short)m.w); a7 += bf2f((unsigned short)(m.w >> 16));
        }
        uint4 p;
        p.x = (unsigned)f2bf(a0) | ((unsigned)f2bf(a1) << 16);
        p.y = (unsigned)f2bf(a2) | ((unsigned)f2bf(a3) << 16);
        p.z = (unsigned)f2bf(a4) | ((unsigned)f2bf(a5) << 16);
        p.w = (unsigned)f2bf(a6) | ((unsigned)f2bf(a7) << 16);
        *(uint4*)(agg2 + (size_t)n * 16 + gl * 8) = p;
    }
}

__global__ void k_bounds(const int* __restrict__ gid, int* __restrict__ start, int nNodes) {
    int t = blockIdx.x * blockDim.x + threadIdx.x;
    if (t > 64) return;
    int lo = 0, hi = nNodes;
    while (lo < hi) {
        int mid = (lo + hi) >> 1;
        if (gid[mid] < t) lo = mid + 1; else hi = mid;
    }
    start[t] = lo;
}

__global__ __launch_bounds__(256) void k_pool(
    const unsigned short* __restrict__ agg2, const int* __restrict__ start,
    float* __restrict__ out) {
    __shared__ float sm[256];
    int g = blockIdx.x;
    int t = threadIdx.x;
    int c = t & 15, idx = t >> 4;
    int s0 = start[g], s1 = start[g + 1];
    float acc = 0.f;
    for (int n = s0 + idx; n < s1; n += 16) acc += fmaxf(bf2f(agg2[(size_t)n * 16 + c]), 0.f);
    sm[t] = acc;
    __syncthreads();
#pragma unroll
    for (int off = 128; off >= 16; off >>= 1) {
        if (t < off) sm[t] += sm[t + off];
        __syncthreads();
    }
    if (t < 16) {
        float cnt = (float)(s1 - s0);
        out[g * 16 + t] = sm[t] / fmaxf(cnt, 1.f);
    }
}

extern "C" void kernel_launch(void* const* d_in, const int* in_sizes, int n_in,
                              void* d_out, int out_size, void* d_ws, size_t ws_size,
                              hipStream_t stream) {
    const float* x      = (const float*)d_in[0];
    const int*   src    = (const int*)d_in[1];
    const int*   dst    = (const int*)d_in[2];
    const int*   et     = (const int*)d_in[3];
    const int*   gid    = (const int*)d_in[4];
    const float* bases1 = (const float*)d_in[5];
    const float* coeff1 = (const float*)d_in[6];
    const float* wself1 = (const float*)d_in[7];
    const float* bias1  = (const float*)d_in[8];
    const float* bases2 = (const float*)d_in[9];
    const float* coeff2 = (const float*)d_in[10];
    const float* wself2 = (const float*)d_in[11];
    const float* bias2  = (const float*)d_in[12];
    float* out = (float*)d_out;

    int nNodes = in_sizes[0] / 64;
    int nE = in_sizes[1];
    int nBins = (nNodes + 255) >> 8;
    int nBh = nBins * NBLK1;

    char* ws = (char*)d_ws;
    unsigned short* W1f  = (unsigned short*)(ws);
    unsigned short* W2f  = (unsigned short*)(ws + 65536);
    unsigned short* W1sf = (unsigned short*)(ws + 81920);
    unsigned short* W2sf = (unsigned short*)(ws + 90112);
    unsigned short* xbf  = (unsigned short*)(ws + 92160);
    unsigned short* agg1 = (unsigned short*)(ws + 12892160);
    unsigned short* agg2 = (unsigned short*)(ws + 25692160);
    int*   payload = (int*)(ws + 28892160);
    int*   skey    = (int*)(ws + 32892160);
    int*   nodeoff = (int*)(ws + 36892160);
    int*   bh      = (int*)(ws + 37292224);
    int*   bhs     = (int*)(ws + 37492416);
    int*   btot    = (int*)(ws + 37692608);
    int*   boff    = (int*)(ws + 37694656);
    int*   start   = (int*)(ws + 37696704);
    unsigned short* xw1 = (unsigned short*)(ws + 37697024);
    unsigned short* xw2 = xw1;   // layer-2 reuses xw1 space

    int tiles = (nNodes + 15) / 16;
    int xwb = (tiles + 3) / 4;
    int scb = (nBh + 255) / 256;

    hipLaunchKernelGGL(k_weights, dim3(8), dim3(256), 0, stream,
                       bases1, coeff1, bases2, coeff2, wself1, wself2,
                       W1f, W2f, W1sf, W2sf);
    hipLaunchKernelGGL(k_cast, dim3(2048), dim3(256), 0, stream,
                       x, xbf, nNodes * 8);
    hipLaunchKernelGGL(k_bhist, dim3(NBLK1), dim3(256), 0, stream,
                       dst, bh, nE, nBins);
    hipLaunchKernelGGL(k_scanblk, dim3(scb), dim3(256), 0, stream,
                       bh, bhs, btot, nBh);
    hipLaunchKernelGGL(k_scantop, dim3(1), dim3(512), 0, stream, btot, boff, scb);
    hipLaunchKernelGGL(k_scanadd2, dim3(scb), dim3(256), 0, stream,
                       bhs, boff, nBh);
    hipLaunchKernelGGL(k_bscat, dim3(NBLK1), dim3(256), 0, stream,
                       dst, src, et, bhs, payload, nE, nBins);
    hipLaunchKernelGGL(k_brefine, dim3(nBins), dim3(256), 0, stream,
                       payload, bhs, skey, nodeoff, nE, nBins, nNodes);
    hipLaunchKernelGGL(k_xw1, dim3(xwb), dim3(256), 0, stream,
                       xbf, W1f, W1sf, bias1, xw1, agg1, nNodes);
    hipLaunchKernelGGL(k_seg1f, dim3(2048), dim3(256), 0, stream,
                       xw1, skey, nodeoff, agg1, nNodes);
    hipLaunchKernelGGL(k_xw2, dim3(xwb), dim3(256), 0, stream,
                       agg1, W2f, W2sf, bias2, xw2, agg2, nNodes);
    hipLaunchKernelGGL(k_seg2f, dim3(1024), dim3(256), 0, stream,
                       xw2, skey, nodeoff, agg2, nNodes);
    hipLaunchKernelGGL(k_bounds, dim3(1), dim3(128), 0, stream, gid, start, nNodes);
    hipLaunchKernelGGL(k_pool, dim3(64), dim3(256), 0, stream, agg2, start, out);
}

// Round 12
// 211.173 us; speedup vs baseline: 3.5552x; 1.0019x over previous
//
#include <hip/hip_runtime.h>

// ---------------------------------------------------------------------------
// RGCN (basis decomposition, 2 layers) + mean-pool.  v12 = v11 plus:
//  - v_cvt_pk_bf16_f32 (1 inst) replaces manual f2bf+pack in xw1/xw2/seg/cast
//  - xw1 LDS transpose stride 36 -> 44 dwords (8-way read conflict -> 2-way)
//
// ws layout (bytes):
//   W1f     us[8*4096]     @ 0          B-frags of W1 (bf16)
//   W2f     us[8*1024]     @ 65536
//   W1sf    us[4096]       @ 81920      wself1 frags
//   W2sf    us[1024]       @ 90112      wself2 frags
//   xbf     us[N*64]       @ 92160      x in bf16
//   agg1    us[N*64]       @ 12892160   layer-1 agg (becomes h)
//   agg2    us[N*16]       @ 25692160   layer-2 agg
//   payload int[E]         @ 28892160   (src*8+et)<<8 | dst&255
//   skey    int[E]         @ 32892160   src*8+et, dst-sorted
//   nodeoff int[N+1]       @ 36892160
//   bh      int[nBins*128] @ 37292224
//   bhs     int[nBins*128] @ 37492416
//   btot    int[512]       @ 37692608
//   boff    int[512]       @ 37694656
//   start   int[65]        @ 37696704
//   xw1     us[N*8*64]     @ 37697024   (102.4 MB; xw2 aliases)
// NEED ~140.1 MB (ws proven >= 166 MB in rounds 5-8)
// ---------------------------------------------------------------------------

typedef __attribute__((ext_vector_type(8))) short bf16x8;
typedef __attribute__((ext_vector_type(4))) float f32x4;

#define NBLK1 128   // blocks for bucket counting sort

__device__ __forceinline__ unsigned short f2bf(float f) {
    unsigned u = __float_as_uint(f);
    unsigned r = u + 0x7FFFu + ((u >> 16) & 1u);   // RNE
    return (unsigned short)(r >> 16);
}

__device__ __forceinline__ float bf2f(unsigned short u) {
    return __uint_as_float(((unsigned)u) << 16);
}

// pack 2 f32 -> 2 bf16 in one dword (RNE), single instruction on gfx950
__device__ __forceinline__ unsigned pk2(float lo, float hi) {
    unsigned r;
    asm("v_cvt_pk_bf16_f32 %0, %1, %2" : "=v"(r) : "v"(lo), "v"(hi));
    return r;
}

// ---- weights in B-fragment order (16x16x32 bf16): lane l holds
// B[k = kt*32+(l>>4)*8+j][n = nt*16+(l&15)], j=0..7.  Also emits wself frags.
__global__ __launch_bounds__(256) void k_weights(
    const float* __restrict__ bases1, const float* __restrict__ coeff1,
    const float* __restrict__ bases2, const float* __restrict__ coeff2,
    const float* __restrict__ wself1, const float* __restrict__ wself2,
    unsigned short* __restrict__ W1f, unsigned short* __restrict__ W2f,
    unsigned short* __restrict__ W1sf, unsigned short* __restrict__ W2sf) {
    int r = blockIdx.x;
    int tid = threadIdx.x;
    float c1[8], c2[8];
#pragma unroll
    for (int b = 0; b < 8; ++b) { c1[b] = coeff1[r * 8 + b]; c2[b] = coeff2[r * 8 + b]; }
    for (int idx = tid; idx < 4096; idx += 256) {
        int j = idx & 7, lane = (idx >> 3) & 63, nt = (idx >> 9) & 3, kt = idx >> 11;
        int i = kt * 32 + ((lane >> 4) << 3) + j;
        int jo = nt * 16 + (lane & 15);
        float s = 0.f;
#pragma unroll
        for (int b = 0; b < 8; ++b) s = fmaf(c1[b], bases1[b * 4096 + i * 64 + jo], s);
        W1f[r * 4096 + idx] = f2bf(s);
        if (r == 0) W1sf[idx] = f2bf(wself1[i * 64 + jo]);
    }
    for (int idx = tid; idx < 1024; idx += 256) {
        int j = idx & 7, lane = (idx >> 3) & 63, kt = idx >> 9;
        int i = kt * 32 + ((lane >> 4) << 3) + j;
        int jo = lane & 15;
        float s = 0.f;
#pragma unroll
        for (int b = 0; b < 8; ++b) s = fmaf(c2[b], bases2[b * 1024 + i * 16 + jo], s);
        W2f[r * 1024 + idx] = f2bf(s);
        if (r == 0) W2sf[idx] = f2bf(wself2[i * 16 + jo]);
    }
}

// ---- x -> bf16 cast (vectorized, cvt_pk)
__global__ __launch_bounds__(256) void k_cast(
    const float* __restrict__ x, unsigned short* __restrict__ xbf, int n8) {
    int stride = gridDim.x * blockDim.x;
    for (int i = blockIdx.x * blockDim.x + threadIdx.x; i < n8; i += stride) {
        f32x4 u0 = *(const f32x4*)(x + (size_t)i * 8);
        f32x4 u1 = *(const f32x4*)(x + (size_t)i * 8 + 4);
        uint4 t;
        t.x = pk2(u0[0], u0[1]);
        t.y = pk2(u0[2], u0[3]);
        t.z = pk2(u1[0], u1[1]);
        t.w = pk2(u1[2], u1[3]);
        *(uint4*)(xbf + (size_t)i * 8) = t;
    }
}

// ---- bucket counting sort by dst>>8: per-block LDS int hist
__global__ __launch_bounds__(256) void k_bhist(
    const int* __restrict__ dst, int* __restrict__ bh, int nE, int nBins) {
    __shared__ int h[512];
    for (int i = threadIdx.x; i < 512; i += 256) h[i] = 0;
    __syncthreads();
    int blk = blockIdx.x;
    int ech = (nE + NBLK1 - 1) / NBLK1;
    int e0 = blk * ech, e1 = min(e0 + ech, nE);
    for (int e = e0 + threadIdx.x; e < e1; e += 256)
        atomicAdd(&h[dst[e] >> 8], 1);
    __syncthreads();
    for (int t = threadIdx.x; t < nBins; t += 256) bh[t * NBLK1 + blk] = h[t];
}

__global__ __launch_bounds__(256) void k_scanblk(
    const int* __restrict__ in, int* __restrict__ outx,
    int* __restrict__ btot, int n) {
    __shared__ int sm[256];
    int tid = threadIdx.x;
    int i = blockIdx.x * 256 + tid;
    int d = (i < n) ? in[i] : 0;
    sm[tid] = d;
    __syncthreads();
#pragma unroll
    for (int off = 1; off < 256; off <<= 1) {
        int v = (tid >= off) ? sm[tid - off] : 0;
        __syncthreads();
        sm[tid] += v;
        __syncthreads();
    }
    if (i < n) outx[i] = sm[tid] - d;
    if (tid == 255) btot[blockIdx.x] = sm[255];
}

__global__ void k_scantop(const int* __restrict__ btot, int* __restrict__ boff, int nB) {
    __shared__ int sm[512];
    int t = threadIdx.x;
    int d = (t < nB) ? btot[t] : 0;
    sm[t] = d;
    __syncthreads();
#pragma unroll
    for (int off = 1; off < 512; off <<= 1) {
        int v = (t >= off) ? sm[t - off] : 0;
        __syncthreads();
        sm[t] += v;
        __syncthreads();
    }
    if (t < nB) boff[t] = sm[t] - d;
}

__global__ __launch_bounds__(256) void k_scanadd2(
    int* __restrict__ bhs, const int* __restrict__ boff, int n) {
    int i = blockIdx.x * 256 + threadIdx.x;
    if (i < n) bhs[i] += boff[i >> 8];
}

// scatter payload into bucket order (LDS int cursors)
__global__ __launch_bounds__(256) void k_bscat(
    const int* __restrict__ dst, const int* __restrict__ src,
    const int* __restrict__ et, const int* __restrict__ bhs,
    int* __restrict__ payload, int nE, int nBins) {
    __shared__ int cur[512];
    int blk = blockIdx.x;
    for (int t = threadIdx.x; t < nBins; t += 256) cur[t] = bhs[t * NBLK1 + blk];
    __syncthreads();
    int ech = (nE + NBLK1 - 1) / NBLK1;
    int e0 = blk * ech, e1 = min(e0 + ech, nE);
    for (int e = e0 + threadIdx.x; e < e1; e += 256) {
        int d = dst[e];
        int pos = atomicAdd(&cur[d >> 8], 1);
        payload[pos] = ((src[e] * 8 + et[e]) << 8) | (d & 255);
    }
}

// per-bucket refine -> per-node CSR (skey, nodeoff)
__global__ __launch_bounds__(256) void k_brefine(
    const int* __restrict__ payload, const int* __restrict__ bhs,
    int* __restrict__ skey, int* __restrict__ nodeoff,
    int nE, int nBins, int nNodes) {
    __shared__ int h[256];
    __shared__ int cur[256];
    __shared__ int sm[256];
    int b = blockIdx.x;
    int e0 = bhs[b * NBLK1];
    int e1 = (b + 1 < nBins) ? bhs[(b + 1) * NBLK1] : nE;
    int t = threadIdx.x;
    h[t] = 0;
    __syncthreads();
    for (int e = e0 + t; e < e1; e += 256)
        atomicAdd(&h[payload[e] & 255], 1);
    __syncthreads();
    int d = h[t];
    sm[t] = d;
    __syncthreads();
#pragma unroll
    for (int off = 1; off < 256; off <<= 1) {
        int v = (t >= off) ? sm[t - off] : 0;
        __syncthreads();
        sm[t] += v;
        __syncthreads();
    }
    int excl = sm[t] - d;
    cur[t] = excl;
    int n = (b << 8) + t;
    if (n < nNodes) nodeoff[n] = e0 + excl;
    __syncthreads();
    for (int e = e0 + t; e < e1; e += 256) {
        int pay = payload[e];
        int pos = atomicAdd(&cur[pay & 255], 1);
        skey[e0 + pos] = pay >> 8;
    }
    if (b == 0 && t == 0) nodeoff[nNodes] = nE;
}

// ---- xw1[(n*8+r)*64] = bf16( x[n] @ W_r ), r=0..7;
//      r=8: agg1[n*64] = bf16( x[n] @ wself1 + bias1 )   (dense MFMA)
#define XW1S 44   // LDS row stride (dwords): 2-way banks on both phases
__global__ __launch_bounds__(256) void k_xw1(
    const unsigned short* __restrict__ xbf,
    const unsigned short* __restrict__ W1f,
    const unsigned short* __restrict__ W1sf,
    const float* __restrict__ bias1,
    unsigned short* __restrict__ xw1, unsigned short* __restrict__ agg1,
    int nNodes) {
    __shared__ unsigned lds[4][16 * XW1S];
    int lane = threadIdx.x & 63;
    int wid = (int)(threadIdx.x >> 6);
    int tile = blockIdx.x * 4 + wid;
    int n0 = tile * 16;
    if (n0 >= nNodes) return;
    int sA = n0 + (lane & 15);
    if (sA >= nNodes) sA = nNodes - 1;
    const unsigned short* xrow = xbf + (size_t)sA * 64 + ((lane >> 4) << 3);
    bf16x8 a[2];
    a[0] = *(const bf16x8*)(xrow);
    a[1] = *(const bf16x8*)(xrow + 32);
    float bj[4];
#pragma unroll
    for (int nt = 0; nt < 4; ++nt) bj[nt] = bias1[nt * 16 + (lane & 15)];
    unsigned* L = lds[wid];
    const int even = !(lane & 1);
    const int cpair = (lane & 14) >> 1;
    int row2 = lane >> 2, ch = lane & 3;
    int nOut = n0 + row2;
    for (int r = 0; r < 9; ++r) {
        const unsigned short* Wf = (r < 8) ? (W1f + r * 4096) : W1sf;
        f32x4 z = {0.f, 0.f, 0.f, 0.f};
        f32x4 acc[4] = {z, z, z, z};
#pragma unroll
        for (int kt = 0; kt < 2; ++kt)
#pragma unroll
            for (int nt = 0; nt < 4; ++nt) {
                bf16x8 b = *(const bf16x8*)(Wf + (kt * 4 + nt) * 512 + lane * 8);
                acc[nt] = __builtin_amdgcn_mfma_f32_16x16x32_bf16(a[kt], b, acc[nt], 0, 0, 0);
            }
        if (r == 8) {
#pragma unroll
            for (int nt = 0; nt < 4; ++nt)
#pragma unroll
                for (int reg = 0; reg < 4; ++reg) acc[nt][reg] += bj[nt];
        }
#pragma unroll
        for (int reg = 0; reg < 4; ++reg) {
            int row = ((lane >> 4) << 2) + reg;
#pragma unroll
            for (int nt = 0; nt < 4; ++nt) {
                float mine = acc[nt][reg];
                float oth = __shfl_xor(mine, 1, 64);
                unsigned pk = even ? pk2(mine, oth) : pk2(oth, mine);
                if (even ? (nt < 2) : (nt >= 2)) L[row * XW1S + cpair + nt * 8] = pk;
            }
        }
        if (nOut < nNodes) {
            uint4 v0 = *(uint4*)&L[row2 * XW1S + ch * 4];
            uint4 v1 = *(uint4*)&L[row2 * XW1S + 16 + ch * 4];
            uint4* mp = (r < 8) ? (uint4*)(xw1 + ((size_t)nOut * 8 + r) * 64)
                                : (uint4*)(agg1 + (size_t)nOut * 64);
            mp[ch] = v0;
            mp[4 + ch] = v1;
        }
    }
}

// ---- fused gather + segment sum + relu, layer1 (8-lane group, uint4/lane)
__global__ __launch_bounds__(256) void k_seg1f(
    const unsigned short* __restrict__ xw1, const int* __restrict__ skey,
    const int* __restrict__ nodeoff, unsigned short* __restrict__ agg1,
    int nNodes) {
    int gl = threadIdx.x & 7;                  // 8 cols per lane
    int grp = (int)((blockIdx.x * blockDim.x + threadIdx.x) >> 3);
    int nG = (int)((gridDim.x * blockDim.x) >> 3);
    for (int n = grp; n < nNodes; n += nG) {
        int s0 = nodeoff[n], s1 = nodeoff[n + 1];
        uint4 v = *(const uint4*)(agg1 + (size_t)n * 64 + gl * 8);
        float a0 = bf2f((unsigned short)v.x), a1 = bf2f((unsigned short)(v.x >> 16));
        float a2 = bf2f((unsigned short)v.y), a3 = bf2f((unsigned short)(v.y >> 16));
        float a4 = bf2f((unsigned short)v.z), a5 = bf2f((unsigned short)(v.z >> 16));
        float a6 = bf2f((unsigned short)v.w), a7 = bf2f((unsigned short)(v.w >> 16));
        for (int i = s0; i < s1; ++i) {
            int key = skey[i];
            uint4 m = *(const uint4*)(xw1 + (size_t)key * 64 + gl * 8);
            a0 += bf2f((unsigned short)m.x); a1 += bf2f((unsigned short)(m.x >> 16));
            a2 += bf2f((unsigned short)m.y); a3 += bf2f((unsigned short)(m.y >> 16));
            a4 += bf2f((unsigned short)m.z); a5 += bf2f((unsigned short)(m.z >> 16));
            a6 += bf2f((unsigned short)m.w); a7 += bf2f((unsigned short)(m.w >> 16));
        }
        // relu (h for layer 2)
        a0 = fmaxf(a0, 0.f); a1 = fmaxf(a1, 0.f); a2 = fmaxf(a2, 0.f);
        a3 = fmaxf(a3, 0.f); a4 = fmaxf(a4, 0.f); a5 = fmaxf(a5, 0.f);
        a6 = fmaxf(a6, 0.f); a7 = fmaxf(a7, 0.f);
        uint4 p;
        p.x = pk2(a0, a1);
        p.y = pk2(a2, a3);
        p.z = pk2(a4, a5);
        p.w = pk2(a6, a7);
        *(uint4*)(agg1 + (size_t)n * 64 + gl * 8) = p;
    }
}

// ---- xw2[(n*8+r)*16] = bf16( h[n] @ W2_r ), r=0..7;
//      r=8: agg2[n*16] = bf16( h[n] @ wself2 + bias2 )
__global__ __launch_bounds__(256) void k_xw2(
    const unsigned short* __restrict__ h,
    const unsigned short* __restrict__ W2f,
    const unsigned short* __restrict__ W2sf,
    const float* __restrict__ bias2,
    unsigned short* __restrict__ xw2, unsigned short* __restrict__ agg2,
    int nNodes) {
    __shared__ unsigned lds[4][16 * 12];
    int lane = threadIdx.x & 63;
    int wid = (int)(threadIdx.x >> 6);
    int tile = blockIdx.x * 4 + wid;
    int n0 = tile * 16;
    if (n0 >= nNodes) return;
    int sA = n0 + (lane & 15);
    if (sA >= nNodes) sA = nNodes - 1;
    const unsigned short* hrow = h + (size_t)sA * 64 + ((lane >> 4) << 3);
    bf16x8 a[2];
    a[0] = *(const bf16x8*)(hrow);
    a[1] = *(const bf16x8*)(hrow + 32);
    float bj = bias2[lane & 15];
    unsigned* L = lds[wid];
    const int even = !(lane & 1);
    const int cpair = (lane & 14) >> 1;
    int row2 = lane >> 1, ch = lane & 1;
    int nOut = n0 + row2;
    for (int r = 0; r < 9; ++r) {
        const unsigned short* Wf = (r < 8) ? (W2f + r * 1024) : W2sf;
        bf16x8 b0 = *(const bf16x8*)(Wf + lane * 8);
        bf16x8 b1 = *(const bf16x8*)(Wf + 512 + lane * 8);
        f32x4 acc = {0.f, 0.f, 0.f, 0.f};
        acc = __builtin_amdgcn_mfma_f32_16x16x32_bf16(a[0], b0, acc, 0, 0, 0);
        acc = __builtin_amdgcn_mfma_f32_16x16x32_bf16(a[1], b1, acc, 0, 0, 0);
        if (r == 8) {
#pragma unroll
            for (int reg = 0; reg < 4; ++reg) acc[reg] += bj;
        }
#pragma unroll
        for (int reg = 0; reg < 4; ++reg) {
            int row = ((lane >> 4) << 2) + reg;
            float mine = acc[reg];
            float oth = __shfl_xor(mine, 1, 64);
            unsigned pk = even ? pk2(mine, oth) : pk2(oth, mine);
            if (even ? (reg < 2) : (reg >= 2)) L[row * 12 + cpair] = pk;
        }
        if (lane < 32 && nOut < nNodes) {
            uint4 v = *(uint4*)&L[row2 * 12 + ch * 4];
            uint4* mp = (r < 8) ? (uint4*)(xw2 + ((size_t)nOut * 8 + r) * 16)
                                : (uint4*)(agg2 + (size_t)nOut * 16);
            mp[ch] = v;
        }
    }
}

// ---- fused gather + segment sum, layer2 (2-lane group, uint4/lane)
__global__ __launch_bounds__(256) void k_seg2f(
    const unsigned short* __restrict__ xw2, const int* __restrict__ skey,
    const int* __restrict__ nodeoff, unsigned short* __restrict__ agg2,
    int nNodes) {
    int gl = threadIdx.x & 1;                  // 8 cols per lane
    int grp = (int)((blockIdx.x * blockDim.x + threadIdx.x) >> 1);
    int nG = (int)((gridDim.x * blockDim.x) >> 1);
    for (int n = grp; n < nNodes; n += nG) {
        int s0 = nodeoff[n], s1 = nodeoff[n + 1];
        uint4 v = *(const uint4*)(agg2 + (size_t)n * 16 + gl * 8);
        float a0 = bf2f((unsigned short)v.x), a1 = bf2f((unsigned short)(v.x >> 16));
        float a2 = bf2f((unsigned short)v.y), a3 = bf2f((unsigned short)(v.y >> 16));
        float a4 = bf2f((unsigned short)v.z), a5 = bf2f((unsigned short)(v.z >> 16));
        float a6 = bf2f((unsigned short)v.w), a7 = bf2f((unsigned short)(v.w >> 16));
        for (int i = s0; i < s1; ++i) {
            int key = skey[i];
            uint4 m = *(const uint4*)(xw2 + (size_t)key * 16 + gl * 8);
            a0 += bf2f((unsigned short)m.x); a1 += bf2f((unsigned short)(m.x >> 16));
            a2 += bf2f((unsigned short)m.y); a3 += bf2f((unsigned short)(m.y >> 16));
            a4 += bf2f((unsigned short)m.z); a5 += bf2f((unsigned short)(m.z >> 16));
            a6 += bf2f((unsigned short)m.w); a7 += bf2f((unsigned short)(m.w >> 16));
        }
        uint4 p;
        p.x = pk2(a0, a1);
        p.y = pk2(a2, a3);
        p.z = pk2(a4, a5);
        p.w = pk2(a6, a7);
        *(uint4*)(agg2 + (size_t)n * 16 + gl * 8) = p;
    }
}

__global__ void k_bounds(const int* __restrict__ gid, int* __restrict__ start, int nNodes) {
    int t = blockIdx.x * blockDim.x + threadIdx.x;
    if (t > 64) return;
    int lo = 0, hi = nNodes;
    while (lo < hi) {
        int mid = (lo + hi) >> 1;
        if (gid[mid] < t) lo = mid + 1; else hi = mid;
    }
    start[t] = lo;
}

__global__ __launch_bounds__(256) void k_pool(
    const unsigned short* __restrict__ agg2, const int* __restrict__ start,
    float* __restrict__ out) {
    __shared__ float sm[256];
    int g = blockIdx.x;
    int t = threadIdx.x;
    int c = t & 15, idx = t >> 4;
    int s0 = start[g], s1 = start[g + 1];
    float acc = 0.f;
    for (int n = s0 + idx; n < s1; n += 16) acc += fmaxf(bf2f(agg2[(size_t)n * 16 + c]), 0.f);
    sm[t] = acc;
    __syncthreads();
#pragma unroll
    for (int off = 128; off >= 16; off >>= 1) {
        if (t < off) sm[t] += sm[t + off];
        __syncthreads();
    }
    if (t < 16) {
        float cnt = (float)(s1 - s0);
        out[g * 16 + t] = sm[t] / fmaxf(cnt, 1.f);
    }
}

extern "C" void kernel_launch(void* const* d_in, const int* in_sizes, int n_in,
                              void* d_out, int out_size, void* d_ws, size_t ws_size,
                              hipStream_t stream) {
    const float* x      = (const float*)d_in[0];
    const int*   src    = (const int*)d_in[1];
    const int*   dst    = (const int*)d_in[2];
    const int*   et     = (const int*)d_in[3];
    const int*   gid    = (const int*)d_in[4];
    const float* bases1 = (const float*)d_in[5];
    const float* coeff1 = (const float*)d_in[6];
    const float* wself1 = (const float*)d_in[7];
    const float* bias1  = (const float*)d_in[8];
    const float* bases2 = (const float*)d_in[9];
    const float* coeff2 = (const float*)d_in[10];
    const float* wself2 = (const float*)d_in[11];
    const float* bias2  = (const float*)d_in[12];
    float* out = (float*)d_out;

    int nNodes = in_sizes[0] / 64;
    int nE = in_sizes[1];
    int nBins = (nNodes + 255) >> 8;
    int nBh = nBins * NBLK1;

    char* ws = (char*)d_ws;
    unsigned short* W1f  = (unsigned short*)(ws);
    unsigned short* W2f  = (unsigned short*)(ws + 65536);
    unsigned short* W1sf = (unsigned short*)(ws + 81920);
    unsigned short* W2sf = (unsigned short*)(ws + 90112);
    unsigned short* xbf  = (unsigned short*)(ws + 92160);
    unsigned short* agg1 = (unsigned short*)(ws + 12892160);
    unsigned short* agg2 = (unsigned short*)(ws + 25692160);
    int*   payload = (int*)(ws + 28892160);
    int*   skey    = (int*)(ws + 32892160);
    int*   nodeoff = (int*)(ws + 36892160);
    int*   bh      = (int*)(ws + 37292224);
    int*   bhs     = (int*)(ws + 37492416);
    int*   btot    = (int*)(ws + 37692608);
    int*   boff    = (int*)(ws + 37694656);
    int*   start   = (int*)(ws + 37696704);
    unsigned short* xw1 = (unsigned short*)(ws + 37697024);
    unsigned short* xw2 = xw1;   // layer-2 reuses xw1 space

    int tiles = (nNodes + 15) / 16;
    int xwb = (tiles + 3) / 4;
    int scb = (nBh + 255) / 256;

    hipLaunchKernelGGL(k_weights, dim3(8), dim3(256), 0, stream,
                       bases1, coeff1, bases2, coeff2, wself1, wself2,
                       W1f, W2f, W1sf, W2sf);
    hipLaunchKernelGGL(k_cast, dim3(2048), dim3(256), 0, stream,
                       x, xbf, nNodes * 8);
    hipLaunchKernelGGL(k_bhist, dim3(NBLK1), dim3(256), 0, stream,
                       dst, bh, nE, nBins);
    hipLaunchKernelGGL(k_scanblk, dim3(scb), dim3(256), 0, stream,
                       bh, bhs, btot, nBh);
    hipLaunchKernelGGL(k_scantop, dim3(1), dim3(512), 0, stream, btot, boff, scb);
    hipLaunchKernelGGL(k_scanadd2, dim3(scb), dim3(256), 0, stream,
                       bhs, boff, nBh);
    hipLaunchKernelGGL(k_bscat, dim3(NBLK1), dim3(256), 0, stream,
                       dst, src, et, bhs, payload, nE, nBins);
    hipLaunchKernelGGL(k_brefine, dim3(nBins), dim3(256), 0, stream,
                       payload, bhs, skey, nodeoff, nE, nBins, nNodes);
    hipLaunchKernelGGL(k_xw1, dim3(xwb), dim3(256), 0, stream,
                       xbf, W1f, W1sf, bias1, xw1, agg1, nNodes);
    hipLaunchKernelGGL(k_seg1f, dim3(2048), dim3(256), 0, stream,
                       xw1, skey, nodeoff, agg1, nNodes);
    hipLaunchKernelGGL(k_xw2, dim3(xwb), dim3(256), 0, stream,
                       agg1, W2f, W2sf, bias2, xw2, agg2, nNodes);
    hipLaunchKernelGGL(k_seg2f, dim3(1024), dim3(256), 0, stream,
                       xw2, skey, nodeoff, agg2, nNodes);
    hipLaunchKernelGGL(k_bounds, dim3(1), dim3(128), 0, stream, gid, start, nNodes);
    hipLaunchKernelGGL(k_pool, dim3(64), dim3(256), 0, stream, agg2, start, out);
}

// Round 13
// 193.947 us; speedup vs baseline: 3.8709x; 1.0888x over previous
//
#include <hip/hip_runtime.h>

// ---------------------------------------------------------------------------
// RGCN (basis decomposition, 2 layers) + mean-pool.  v13 = v12 plus:
//  - k_cast deleted: xw1 reads f32 x directly, converts in-register (cvt_pk)
//  - seg1f/seg2f gather loops unrolled x4 (4 independent gathers in flight)
//  - k_bounds fused into k_pool (binary search in-kernel)
//
// ws layout (bytes):
//   W1f     us[8*4096]     @ 0          B-frags of W1 (bf16)
//   W2f     us[8*1024]     @ 65536
//   W1sf    us[4096]       @ 81920      wself1 frags
//   W2sf    us[1024]       @ 90112      wself2 frags
//   (xbf slot unused)      @ 92160
//   agg1    us[N*64]       @ 12892160   layer-1 agg (becomes h)
//   agg2    us[N*16]       @ 25692160   layer-2 agg
//   payload int[E]         @ 28892160   (src*8+et)<<8 | dst&255
//   skey    int[E]         @ 32892160   src*8+et, dst-sorted
//   nodeoff int[N+1]       @ 36892160
//   bh      int[nBins*128] @ 37292224
//   bhs     int[nBins*128] @ 37492416
//   btot    int[512]       @ 37692608
//   boff    int[512]       @ 37694656
//   xw1     us[N*8*64]     @ 37697024   (102.4 MB; xw2 aliases)
// NEED ~140.1 MB (ws proven >= 166 MB in rounds 5-8)
// ---------------------------------------------------------------------------

typedef __attribute__((ext_vector_type(8))) short bf16x8;
typedef __attribute__((ext_vector_type(4))) float f32x4;

#define NBLK1 128   // blocks for bucket counting sort

__device__ __forceinline__ unsigned short f2bf(float f) {
    unsigned u = __float_as_uint(f);
    unsigned r = u + 0x7FFFu + ((u >> 16) & 1u);   // RNE
    return (unsigned short)(r >> 16);
}

__device__ __forceinline__ float bf2f(unsigned short u) {
    return __uint_as_float(((unsigned)u) << 16);
}

// pack 2 f32 -> 2 bf16 in one dword (RNE), single instruction on gfx950
__device__ __forceinline__ unsigned pk2(float lo, float hi) {
    unsigned r;
    asm("v_cvt_pk_bf16_f32 %0, %1, %2" : "=v"(r) : "v"(lo), "v"(hi));
    return r;
}

union cv16 { uint4 u; bf16x8 b; };

// ---- weights in B-fragment order (16x16x32 bf16): lane l holds
// B[k = kt*32+(l>>4)*8+j][n = nt*16+(l&15)], j=0..7.  Also emits wself frags.
__global__ __launch_bounds__(256) void k_weights(
    const float* __restrict__ bases1, const float* __restrict__ coeff1,
    const float* __restrict__ bases2, const float* __restrict__ coeff2,
    const float* __restrict__ wself1, const float* __restrict__ wself2,
    unsigned short* __restrict__ W1f, unsigned short* __restrict__ W2f,
    unsigned short* __restrict__ W1sf, unsigned short* __restrict__ W2sf) {
    int r = blockIdx.x;
    int tid = threadIdx.x;
    float c1[8], c2[8];
#pragma unroll
    for (int b = 0; b < 8; ++b) { c1[b] = coeff1[r * 8 + b]; c2[b] = coeff2[r * 8 + b]; }
    for (int idx = tid; idx < 4096; idx += 256) {
        int j = idx & 7, lane = (idx >> 3) & 63, nt = (idx >> 9) & 3, kt = idx >> 11;
        int i = kt * 32 + ((lane >> 4) << 3) + j;
        int jo = nt * 16 + (lane & 15);
        float s = 0.f;
#pragma unroll
        for (int b = 0; b < 8; ++b) s = fmaf(c1[b], bases1[b * 4096 + i * 64 + jo], s);
        W1f[r * 4096 + idx] = f2bf(s);
        if (r == 0) W1sf[idx] = f2bf(wself1[i * 64 + jo]);
    }
    for (int idx = tid; idx < 1024; idx += 256) {
        int j = idx & 7, lane = (idx >> 3) & 63, kt = idx >> 9;
        int i = kt * 32 + ((lane >> 4) << 3) + j;
        int jo = lane & 15;
        float s = 0.f;
#pragma unroll
        for (int b = 0; b < 8; ++b) s = fmaf(c2[b], bases2[b * 1024 + i * 16 + jo], s);
        W2f[r * 1024 + idx] = f2bf(s);
        if (r == 0) W2sf[idx] = f2bf(wself2[i * 16 + jo]);
    }
}

// ---- bucket counting sort by dst>>8: per-block LDS int hist
__global__ __launch_bounds__(256) void k_bhist(
    const int* __restrict__ dst, int* __restrict__ bh, int nE, int nBins) {
    __shared__ int h[512];
    for (int i = threadIdx.x; i < 512; i += 256) h[i] = 0;
    __syncthreads();
    int blk = blockIdx.x;
    int ech = (nE + NBLK1 - 1) / NBLK1;
    int e0 = blk * ech, e1 = min(e0 + ech, nE);
    for (int e = e0 + threadIdx.x; e < e1; e += 256)
        atomicAdd(&h[dst[e] >> 8], 1);
    __syncthreads();
    for (int t = threadIdx.x; t < nBins; t += 256) bh[t * NBLK1 + blk] = h[t];
}

__global__ __launch_bounds__(256) void k_scanblk(
    const int* __restrict__ in, int* __restrict__ outx,
    int* __restrict__ btot, int n) {
    __shared__ int sm[256];
    int tid = threadIdx.x;
    int i = blockIdx.x * 256 + tid;
    int d = (i < n) ? in[i] : 0;
    sm[tid] = d;
    __syncthreads();
#pragma unroll
    for (int off = 1; off < 256; off <<= 1) {
        int v = (tid >= off) ? sm[tid - off] : 0;
        __syncthreads();
        sm[tid] += v;
        __syncthreads();
    }
    if (i < n) outx[i] = sm[tid] - d;
    if (tid == 255) btot[blockIdx.x] = sm[255];
}

__global__ void k_scantop(const int* __restrict__ btot, int* __restrict__ boff, int nB) {
    __shared__ int sm[512];
    int t = threadIdx.x;
    int d = (t < nB) ? btot[t] : 0;
    sm[t] = d;
    __syncthreads();
#pragma unroll
    for (int off = 1; off < 512; off <<= 1) {
        int v = (t >= off) ? sm[t - off] : 0;
        __syncthreads();
        sm[t] += v;
        __syncthreads();
    }
    if (t < nB) boff[t] = sm[t] - d;
}

__global__ __launch_bounds__(256) void k_scanadd2(
    int* __restrict__ bhs, const int* __restrict__ boff, int n) {
    int i = blockIdx.x * 256 + threadIdx.x;
    if (i < n) bhs[i] += boff[i >> 8];
}

// scatter payload into bucket order (LDS int cursors)
__global__ __launch_bounds__(256) void k_bscat(
    const int* __restrict__ dst, const int* __restrict__ src,
    const int* __restrict__ et, const int* __restrict__ bhs,
    int* __restrict__ payload, int nE, int nBins) {
    __shared__ int cur[512];
    int blk = blockIdx.x;
    for (int t = threadIdx.x; t < nBins; t += 256) cur[t] = bhs[t * NBLK1 + blk];
    __syncthreads();
    int ech = (nE + NBLK1 - 1) / NBLK1;
    int e0 = blk * ech, e1 = min(e0 + ech, nE);
    for (int e = e0 + threadIdx.x; e < e1; e += 256) {
        int d = dst[e];
        int pos = atomicAdd(&cur[d >> 8], 1);
        payload[pos] = ((src[e] * 8 + et[e]) << 8) | (d & 255);
    }
}

// per-bucket refine -> per-node CSR (skey, nodeoff)
__global__ __launch_bounds__(256) void k_brefine(
    const int* __restrict__ payload, const int* __restrict__ bhs,
    int* __restrict__ skey, int* __restrict__ nodeoff,
    int nE, int nBins, int nNodes) {
    __shared__ int h[256];
    __shared__ int cur[256];
    __shared__ int sm[256];
    int b = blockIdx.x;
    int e0 = bhs[b * NBLK1];
    int e1 = (b + 1 < nBins) ? bhs[(b + 1) * NBLK1] : nE;
    int t = threadIdx.x;
    h[t] = 0;
    __syncthreads();
    for (int e = e0 + t; e < e1; e += 256)
        atomicAdd(&h[payload[e] & 255], 1);
    __syncthreads();
    int d = h[t];
    sm[t] = d;
    __syncthreads();
#pragma unroll
    for (int off = 1; off < 256; off <<= 1) {
        int v = (t >= off) ? sm[t - off] : 0;
        __syncthreads();
        sm[t] += v;
        __syncthreads();
    }
    int excl = sm[t] - d;
    cur[t] = excl;
    int n = (b << 8) + t;
    if (n < nNodes) nodeoff[n] = e0 + excl;
    __syncthreads();
    for (int e = e0 + t; e < e1; e += 256) {
        int pay = payload[e];
        int pos = atomicAdd(&cur[pay & 255], 1);
        skey[e0 + pos] = pay >> 8;
    }
    if (b == 0 && t == 0) nodeoff[nNodes] = nE;
}

// ---- xw1[(n*8+r)*64] = bf16( x[n] @ W_r ), r=0..7;
//      r=8: agg1[n*64] = bf16( x[n] @ wself1 + bias1 )   (dense MFMA)
//      reads f32 x directly; converts A-frags in-register (cvt_pk)
#define XW1S 44   // LDS row stride (dwords)
__global__ __launch_bounds__(256) void k_xw1(
    const float* __restrict__ x,
    const unsigned short* __restrict__ W1f,
    const unsigned short* __restrict__ W1sf,
    const float* __restrict__ bias1,
    unsigned short* __restrict__ xw1, unsigned short* __restrict__ agg1,
    int nNodes) {
    __shared__ unsigned lds[4][16 * XW1S];
    int lane = threadIdx.x & 63;
    int wid = (int)(threadIdx.x >> 6);
    int tile = blockIdx.x * 4 + wid;
    int n0 = tile * 16;
    if (n0 >= nNodes) return;
    int sA = n0 + (lane & 15);
    if (sA >= nNodes) sA = nNodes - 1;
    const float* xrow = x + (size_t)sA * 64 + ((lane >> 4) << 3);
    bf16x8 a[2];
#pragma unroll
    for (int kt = 0; kt < 2; ++kt) {
        f32x4 u0 = *(const f32x4*)(xrow + kt * 32);
        f32x4 u1 = *(const f32x4*)(xrow + kt * 32 + 4);
        cv16 c;
        c.u.x = pk2(u0[0], u0[1]);
        c.u.y = pk2(u0[2], u0[3]);
        c.u.z = pk2(u1[0], u1[1]);
        c.u.w = pk2(u1[2], u1[3]);
        a[kt] = c.b;
    }
    float bj[4];
#pragma unroll
    for (int nt = 0; nt < 4; ++nt) bj[nt] = bias1[nt * 16 + (lane & 15)];
    unsigned* L = lds[wid];
    const int even = !(lane & 1);
    const int cpair = (lane & 14) >> 1;
    int row2 = lane >> 2, ch = lane & 3;
    int nOut = n0 + row2;
    for (int r = 0; r < 9; ++r) {
        const unsigned short* Wf = (r < 8) ? (W1f + r * 4096) : W1sf;
        f32x4 z = {0.f, 0.f, 0.f, 0.f};
        f32x4 acc[4] = {z, z, z, z};
#pragma unroll
        for (int kt = 0; kt < 2; ++kt)
#pragma unroll
            for (int nt = 0; nt < 4; ++nt) {
                bf16x8 b = *(const bf16x8*)(Wf + (kt * 4 + nt) * 512 + lane * 8);
                acc[nt] = __builtin_amdgcn_mfma_f32_16x16x32_bf16(a[kt], b, acc[nt], 0, 0, 0);
            }
        if (r == 8) {
#pragma unroll
            for (int nt = 0; nt < 4; ++nt)
#pragma unroll
                for (int reg = 0; reg < 4; ++reg) acc[nt][reg] += bj[nt];
        }
#pragma unroll
        for (int reg = 0; reg < 4; ++reg) {
            int row = ((lane >> 4) << 2) + reg;
#pragma unroll
            for (int nt = 0; nt < 4; ++nt) {
                float mine = acc[nt][reg];
                float oth = __shfl_xor(mine, 1, 64);
                unsigned pk = even ? pk2(mine, oth) : pk2(oth, mine);
                if (even ? (nt < 2) : (nt >= 2)) L[row * XW1S + cpair + nt * 8] = pk;
            }
        }
        if (nOut < nNodes) {
            uint4 v0 = *(uint4*)&L[row2 * XW1S + ch * 4];
            uint4 v1 = *(uint4*)&L[row2 * XW1S + 16 + ch * 4];
            uint4* mp = (r < 8) ? (uint4*)(xw1 + ((size_t)nOut * 8 + r) * 64)
                                : (uint4*)(agg1 + (size_t)nOut * 64);
            mp[ch] = v0;
            mp[4 + ch] = v1;
        }
    }
}

__device__ __forceinline__ void acc8(uint4 m, float* a) {
    a[0] += bf2f((unsigned short)m.x); a[1] += bf2f((unsigned short)(m.x >> 16));
    a[2] += bf2f((unsigned short)m.y); a[3] += bf2f((unsigned short)(m.y >> 16));
    a[4] += bf2f((unsigned short)m.z); a[5] += bf2f((unsigned short)(m.z >> 16));
    a[6] += bf2f((unsigned short)m.w); a[7] += bf2f((unsigned short)(m.w >> 16));
}

// ---- fused gather + segment sum + relu, layer1 (8-lane group, uint4/lane,
//      unroll-4: 4 independent gathers in flight)
__global__ __launch_bounds__(256) void k_seg1f(
    const unsigned short* __restrict__ xw1, const int* __restrict__ skey,
    const int* __restrict__ nodeoff, unsigned short* __restrict__ agg1,
    int nNodes) {
    int gl = threadIdx.x & 7;                  // 8 cols per lane
    int grp = (int)((blockIdx.x * blockDim.x + threadIdx.x) >> 3);
    int nG = (int)((gridDim.x * blockDim.x) >> 3);
    for (int n = grp; n < nNodes; n += nG) {
        int s0 = nodeoff[n], s1 = nodeoff[n + 1];
        uint4 v = *(const uint4*)(agg1 + (size_t)n * 64 + gl * 8);
        float a[8];
        a[0] = bf2f((unsigned short)v.x); a[1] = bf2f((unsigned short)(v.x >> 16));
        a[2] = bf2f((unsigned short)v.y); a[3] = bf2f((unsigned short)(v.y >> 16));
        a[4] = bf2f((unsigned short)v.z); a[5] = bf2f((unsigned short)(v.z >> 16));
        a[6] = bf2f((unsigned short)v.w); a[7] = bf2f((unsigned short)(v.w >> 16));
        int i = s0;
        for (; i + 4 <= s1; i += 4) {
            int k0 = skey[i], k1 = skey[i + 1], k2 = skey[i + 2], k3 = skey[i + 3];
            uint4 m0 = *(const uint4*)(xw1 + (size_t)k0 * 64 + gl * 8);
            uint4 m1 = *(const uint4*)(xw1 + (size_t)k1 * 64 + gl * 8);
            uint4 m2 = *(const uint4*)(xw1 + (size_t)k2 * 64 + gl * 8);
            uint4 m3 = *(const uint4*)(xw1 + (size_t)k3 * 64 + gl * 8);
            acc8(m0, a); acc8(m1, a); acc8(m2, a); acc8(m3, a);
        }
        for (; i < s1; ++i) {
            int key = skey[i];
            uint4 m = *(const uint4*)(xw1 + (size_t)key * 64 + gl * 8);
            acc8(m, a);
        }
#pragma unroll
        for (int q = 0; q < 8; ++q) a[q] = fmaxf(a[q], 0.f);   // relu -> h
        uint4 p;
        p.x = pk2(a[0], a[1]);
        p.y = pk2(a[2], a[3]);
        p.z = pk2(a[4], a[5]);
        p.w = pk2(a[6], a[7]);
        *(uint4*)(agg1 + (size_t)n * 64 + gl * 8) = p;
    }
}

// ---- xw2[(n*8+r)*16] = bf16( h[n] @ W2_r ), r=0..7;
//      r=8: agg2[n*16] = bf16( h[n] @ wself2 + bias2 )
__global__ __launch_bounds__(256) void k_xw2(
    const unsigned short* __restrict__ h,
    const unsigned short* __restrict__ W2f,
    const unsigned short* __restrict__ W2sf,
    const float* __restrict__ bias2,
    unsigned short* __restrict__ xw2, unsigned short* __restrict__ agg2,
    int nNodes) {
    __shared__ unsigned lds[4][16 * 12];
    int lane = threadIdx.x & 63;
    int wid = (int)(threadIdx.x >> 6);
    int tile = blockIdx.x * 4 + wid;
    int n0 = tile * 16;
    if (n0 >= nNodes) return;
    int sA = n0 + (lane & 15);
    if (sA >= nNodes) sA = nNodes - 1;
    const unsigned short* hrow = h + (size_t)sA * 64 + ((lane >> 4) << 3);
    bf16x8 a[2];
    a[0] = *(const bf16x8*)(hrow);
    a[1] = *(const bf16x8*)(hrow + 32);
    float bj = bias2[lane & 15];
    unsigned* L = lds[wid];
    const int even = !(lane & 1);
    const int cpair = (lane & 14) >> 1;
    int row2 = lane >> 1, ch = lane & 1;
    int nOut = n0 + row2;
    for (int r = 0; r < 9; ++r) {
        const unsigned short* Wf = (r < 8) ? (W2f + r * 1024) : W2sf;
        bf16x8 b0 = *(const bf16x8*)(Wf + lane * 8);
        bf16x8 b1 = *(const bf16x8*)(Wf + 512 + lane * 8);
        f32x4 acc = {0.f, 0.f, 0.f, 0.f};
        acc = __builtin_amdgcn_mfma_f32_16x16x32_bf16(a[0], b0, acc, 0, 0, 0);
        acc = __builtin_amdgcn_mfma_f32_16x16x32_bf16(a[1], b1, acc, 0, 0, 0);
        if (r == 8) {
#pragma unroll
            for (int reg = 0; reg < 4; ++reg) acc[reg] += bj;
        }
#pragma unroll
        for (int reg = 0; reg < 4; ++reg) {
            int row = ((lane >> 4) << 2) + reg;
            float mine = acc[reg];
            float oth = __shfl_xor(mine, 1, 64);
            unsigned pk = even ? pk2(mine, oth) : pk2(oth, mine);
            if (even ? (reg < 2) : (reg >= 2)) L[row * 12 + cpair] = pk;
        }
        if (lane < 32 && nOut < nNodes) {
            uint4 v = *(uint4*)&L[row2 * 12 + ch * 4];
            uint4* mp = (r < 8) ? (uint4*)(xw2 + ((size_t)nOut * 8 + r) * 16)
                                : (uint4*)(agg2 + (size_t)nOut * 16);
            mp[ch] = v;
        }
    }
}

// ---- fused gather + segment sum, layer2 (2-lane group, uint4/lane, unroll-4)
__global__ __launch_bounds__(256) void k_seg2f(
    const unsigned short* __restrict__ xw2, const int* __restrict__ skey,
    const int* __restrict__ nodeoff, unsigned short* __restrict__ agg2,
    int nNodes) {
    int gl = threadIdx.x & 1;                  // 8 cols per lane
    int grp = (int)((blockIdx.x * blockDim.x + threadIdx.x) >> 1);
    int nG = (int)((gridDim.x * blockDim.x) >> 1);
    for (int n = grp; n < nNodes; n += nG) {
        int s0 = nodeoff[n], s1 = nodeoff[n + 1];
        uint4 v = *(const uint4*)(agg2 + (size_t)n * 16 + gl * 8);
        float a[8];
        a[0] = bf2f((unsigned short)v.x); a[1] = bf2f((unsigned short)(v.x >> 16));
        a[2] = bf2f((unsigned short)v.y); a[3] = bf2f((unsigned short)(v.y >> 16));
        a[4] = bf2f((unsigned short)v.z); a[5] = bf2f((unsigned short)(v.z >> 16));
        a[6] = bf2f((unsigned short)v.w); a[7] = bf2f((unsigned short)(v.w >> 16));
        int i = s0;
        for (; i + 4 <= s1; i += 4) {
            int k0 = skey[i], k1 = skey[i + 1], k2 = skey[i + 2], k3 = skey[i + 3];
            uint4 m0 = *(const uint4*)(xw2 + (size_t)k0 * 16 + gl * 8);
            uint4 m1 = *(const uint4*)(xw2 + (size_t)k1 * 16 + gl * 8);
            uint4 m2 = *(const uint4*)(xw2 + (size_t)k2 * 16 + gl * 8);
            uint4 m3 = *(const uint4*)(xw2 + (size_t)k3 * 16 + gl * 8);
            acc8(m0, a); acc8(m1, a); acc8(m2, a); acc8(m3, a);
        }
        for (; i < s1; ++i) {
            int key = skey[i];
            uint4 m = *(const uint4*)(xw2 + (size_t)key * 16 + gl * 8);
            acc8(m, a);
        }
        uint4 p;
        p.x = pk2(a[0], a[1]);
        p.y = pk2(a[2], a[3]);
        p.z = pk2(a[4], a[5]);
        p.w = pk2(a[6], a[7]);
        *(uint4*)(agg2 + (size_t)n * 16 + gl * 8) = p;
    }
}

// ---- mean-pool with fused graph-boundary binary search
__global__ __launch_bounds__(256) void k_pool(
    const unsigned short* __restrict__ agg2, const int* __restrict__ gid,
    float* __restrict__ out, int nNodes) {
    __shared__ float sm[256];
    __shared__ int bnd[2];
    int g = blockIdx.x;
    int t = threadIdx.x;
    if (t < 2) {
        int target = g + t;
        int lo = 0, hi = nNodes;
        while (lo < hi) {
            int mid = (lo + hi) >> 1;
            if (gid[mid] < target) lo = mid + 1; else hi = mid;
        }
        bnd[t] = lo;
    }
    __syncthreads();
    int s0 = bnd[0], s1 = bnd[1];
    int c = t & 15, idx = t >> 4;
    float acc = 0.f;
    for (int n = s0 + idx; n < s1; n += 16) acc += fmaxf(bf2f(agg2[(size_t)n * 16 + c]), 0.f);
    sm[t] = acc;
    __syncthreads();
#pragma unroll
    for (int off = 128; off >= 16; off >>= 1) {
        if (t < off) sm[t] += sm[t + off];
        __syncthreads();
    }
    if (t < 16) {
        float cnt = (float)(s1 - s0);
        out[g * 16 + t] = sm[t] / fmaxf(cnt, 1.f);
    }
}

extern "C" void kernel_launch(void* const* d_in, const int* in_sizes, int n_in,
                              void* d_out, int out_size, void* d_ws, size_t ws_size,
                              hipStream_t stream) {
    const float* x      = (const float*)d_in[0];
    const int*   src    = (const int*)d_in[1];
    const int*   dst    = (const int*)d_in[2];
    const int*   et     = (const int*)d_in[3];
    const int*   gid    = (const int*)d_in[4];
    const float* bases1 = (const float*)d_in[5];
    const float* coeff1 = (const float*)d_in[6];
    const float* wself1 = (const float*)d_in[7];
    const float* bias1  = (const float*)d_in[8];
    const float* bases2 = (const float*)d_in[9];
    const float* coeff2 = (const float*)d_in[10];
    const float* wself2 = (const float*)d_in[11];
    const float* bias2  = (const float*)d_in[12];
    float* out = (float*)d_out;

    int nNodes = in_sizes[0] / 64;
    int nE = in_sizes[1];
    int nBins = (nNodes + 255) >> 8;
    int nBh = nBins * NBLK1;

    char* ws = (char*)d_ws;
    unsigned short* W1f  = (unsigned short*)(ws);
    unsigned short* W2f  = (unsigned short*)(ws + 65536);
    unsigned short* W1sf = (unsigned short*)(ws + 81920);
    unsigned short* W2sf = (unsigned short*)(ws + 90112);
    unsigned short* agg1 = (unsigned short*)(ws + 12892160);
    unsigned short* agg2 = (unsigned short*)(ws + 25692160);
    int*   payload = (int*)(ws + 28892160);
    int*   skey    = (int*)(ws + 32892160);
    int*   nodeoff = (int*)(ws + 36892160);
    int*   bh      = (int*)(ws + 37292224);
    int*   bhs     = (int*)(ws + 37492416);
    int*   btot    = (int*)(ws + 37692608);
    int*   boff    = (int*)(ws + 37694656);
    unsigned short* xw1 = (unsigned short*)(ws + 37697024);
    unsigned short* xw2 = xw1;   // layer-2 reuses xw1 space

    int tiles = (nNodes + 15) / 16;
    int xwb = (tiles + 3) / 4;
    int scb = (nBh + 255) / 256;

    hipLaunchKernelGGL(k_weights, dim3(8), dim3(256), 0, stream,
                       bases1, coeff1, bases2, coeff2, wself1, wself2,
                       W1f, W2f, W1sf, W2sf);
    hipLaunchKernelGGL(k_bhist, dim3(NBLK1), dim3(256), 0, stream,
                       dst, bh, nE, nBins);
    hipLaunchKernelGGL(k_scanblk, dim3(scb), dim3(256), 0, stream,
                       bh, bhs, btot, nBh);
    hipLaunchKernelGGL(k_scantop, dim3(1), dim3(512), 0, stream, btot, boff, scb);
    hipLaunchKernelGGL(k_scanadd2, dim3(scb), dim3(256), 0, stream,
                       bhs, boff, nBh);
    hipLaunchKernelGGL(k_bscat, dim3(NBLK1), dim3(256), 0, stream,
                       dst, src, et, bhs, payload, nE, nBins);
    hipLaunchKernelGGL(k_brefine, dim3(nBins), dim3(256), 0, stream,
                       payload, bhs, skey, nodeoff, nE, nBins, nNodes);
    hipLaunchKernelGGL(k_xw1, dim3(xwb), dim3(256), 0, stream,
                       x, W1f, W1sf, bias1, xw1, agg1, nNodes);
    hipLaunchKernelGGL(k_seg1f, dim3(2048), dim3(256), 0, stream,
                       xw1, skey, nodeoff, agg1, nNodes);
    hipLaunchKernelGGL(k_xw2, dim3(xwb), dim3(256), 0, stream,
                       agg1, W2f, W2sf, bias2, xw2, agg2, nNodes);
    hipLaunchKernelGGL(k_seg2f, dim3(1024), dim3(256), 0, stream,
                       xw2, skey, nodeoff, agg2, nNodes);
    hipLaunchKernelGGL(k_pool, dim3(64), dim3(256), 0, stream,
                       agg2, gid, out, nNodes);
}